// Round 4
// baseline (7009.753 us; speedup 1.0000x reference)
//
#include <hip/hip_runtime.h>
#include <hip/hip_bf16.h>

// BDLOTreeLSTM on MI355X — round 4: fused chains (M=32), one barrier/step,
// double-buffered LDS A-tiles, explicit B-prefetch ring in registers.

constexpr int Hd    = 256;
constexpr int NBv   = 3;
constexpr int NVv   = 64;
constexpr int BATCH = 512;
constexpr long long NROWS = (long long)BATCH * NBv * NVv;   // 98304
constexpr int CLEN = 40;
constexpr int CI0 = 16, CI1 = 48;

typedef __hip_bfloat16 bf16;
typedef unsigned short ushort;
typedef __attribute__((ext_vector_type(8))) short short8;
typedef __attribute__((ext_vector_type(4))) float f32x4;

__device__ __forceinline__ float sigf(float x)   { return 1.f / (1.f + __expf(-x)); }
__device__ __forceinline__ float tanh_f(float x) { return 1.f - 2.f / (__expf(2.f * x) + 1.f); }

__device__ __forceinline__ ushort f2bf(float x) {
  unsigned u = __float_as_uint(x);
  return (ushort)((u + 0x7FFFu + ((u >> 16) & 1u)) >> 16);   // RNE
}

// ================= weight packing (round-3, verified) =========================
__global__ __launch_bounds__(256) void pack_bu_kernel(
    const float* __restrict__ W_iou, const float* __restrict__ W_f,
    const float* __restrict__ U_iou, const float* __restrict__ U_f,
    ushort* __restrict__ out)   // [512 K][1024 N]: [[W_iou|W_f];[U_iou|U_f]]
{
  int idx = blockIdx.x * 256 + threadIdx.x;
  int j = idx & 7, l = (idx >> 3) & 63, T = idx >> 9;
  int ks = T & 15, nt = T >> 4;
  int k = ks * 32 + (l >> 4) * 8 + j;
  int n = nt * 16 + (l & 15);
  float v;
  if (k < 256) v = (n < 768) ? W_iou[k * 768 + n] : W_f[k * 256 + (n - 768)];
  else         v = (n < 768) ? U_iou[(k - 256) * 768 + n] : U_f[(k - 256) * 256 + (n - 768)];
  out[idx] = f2bf(v);
}

__global__ __launch_bounds__(256) void pack_td_kernel(
    const float* __restrict__ W_ih, const float* __restrict__ W_hh,
    ushort* __restrict__ out)   // [512][1024]: [[W_ih];[W_hh]]
{
  int idx = blockIdx.x * 256 + threadIdx.x;
  int j = idx & 7, l = (idx >> 3) & 63, T = idx >> 9;
  int ks = T & 15, nt = T >> 4;
  int k = ks * 32 + (l >> 4) * 8 + j;
  int n = nt * 16 + (l & 15);
  float v = (k < 256) ? W_ih[k * 1024 + n] : W_hh[(k - 256) * 1024 + n];
  out[idx] = f2bf(v);
}

__global__ __launch_bounds__(256) void pack_wfx_kernel(
    const float* __restrict__ W_f, ushort* __restrict__ out)   // [256][256]
{
  int idx = blockIdx.x * 256 + threadIdx.x;
  int j = idx & 7, l = (idx >> 3) & 63, T = idx >> 9;
  int ks = T & 7, nt = T >> 3;
  int k = ks * 32 + (l >> 4) * 8 + j;
  int n = nt * 16 + (l & 15);
  out[idx] = f2bf(W_f[k * 256 + n]);
}

// ================= fused encoder (round-2, known-good) ========================
__global__ __launch_bounds__(256) void enc_kernel(
    const float* __restrict__ cv, const float* __restrict__ pv,
    const float* __restrict__ hints,
    const float* __restrict__ w1, const float* __restrict__ b1,
    const float* __restrict__ w2, const float* __restrict__ b2,
    bf16* __restrict__ enc)
{
  __shared__ float fs[8][9];
  __shared__ float h1s[8][Hd];
  long long row0 = (long long)blockIdx.x * 8;
  int tid = threadIdx.x;
  if (tid < 72) {
    int r = tid / 9, i = tid % 9;
    long long row = row0 + r;
    float v;
    if (i < 3)      v = cv[row * 3 + i];
    else if (i < 6) v = cv[row * 3 + (i - 3)] - pv[row * 3 + (i - 3)];
    else            v = hints[row * 3 + (i - 6)];
    fs[r][i] = v;
  }
  __syncthreads();
  int j = tid;
  {
    float w[9];
#pragma unroll
    for (int i = 0; i < 9; i++) w[i] = w1[i * Hd + j];
    float bb = b1[j];
#pragma unroll
    for (int r = 0; r < 8; r++) {
      float a = bb;
#pragma unroll
      for (int i = 0; i < 9; i++) a += fs[r][i] * w[i];
      h1s[r][j] = fmaxf(a, 0.f);
    }
  }
  __syncthreads();
  float acc[8];
  float bb2 = b2[j];
#pragma unroll
  for (int r = 0; r < 8; r++) acc[r] = bb2;
  for (int t = 0; t < Hd; t++) {
    float w = w2[t * Hd + j];
#pragma unroll
    for (int r = 0; r < 8; r++) acc[r] += h1s[r][t] * w;
  }
#pragma unroll
  for (int r = 0; r < 8; r++) enc[(row0 + r) * Hd + j] = __float2bfloat16(acc[r]);
}

// ================= seq kernel helpers =========================================
__device__ __forceinline__ short8 ldA(const ushort* buf, int row, int kbyte) {
  int off = (row * 512 + kbyte) ^ ((row & 7) << 4);
  return *(const short8*)((const char*)buf + off);
}

// Main GEMM: A [MT*16 x 512] = [Ax | Ah], B = W (frag-packed), N-slice per wave.
template<int MT>
__device__ __forceinline__ void gemm_main(
    const ushort* __restrict__ W, const ushort* __restrict__ Axb_,
    const ushort* __restrict__ Ahb_, f32x4 (&acc)[MT][4][2],
    int w, int lane)
{
  const int col = lane & 15;
  const int kb  = (lane >> 4) * 16;
  short8 B[2][4][2];
  short8 A[2][MT];
#pragma unroll
  for (int g = 0; g < 4; ++g)
#pragma unroll
    for (int p = 0; p < 2; ++p)
      B[0][g][p] = *(const short8*)(W + (((g * 16 + 2 * w + p) * 16) * 64 + lane) * 8);
#pragma unroll
  for (int m = 0; m < MT; ++m)
    A[0][m] = ldA(Axb_, m * 16 + col, kb);
#pragma unroll
  for (int ks = 0; ks < 16; ++ks) {
    const int cur = ks & 1, nxt = cur ^ 1;
    if (ks < 15) {
      const int k1 = ks + 1;
      const ushort* Ab = (k1 < 8) ? Axb_ : Ahb_;
      const int kk = k1 & 7;
#pragma unroll
      for (int g = 0; g < 4; ++g)
#pragma unroll
        for (int p = 0; p < 2; ++p)
          B[nxt][g][p] = *(const short8*)(W + (((g * 16 + 2 * w + p) * 16 + k1) * 64 + lane) * 8);
#pragma unroll
      for (int m = 0; m < MT; ++m)
        A[nxt][m] = ldA(Ab, m * 16 + col, kk * 64 + kb);
    }
#pragma unroll
    for (int g = 0; g < 4; ++g)
#pragma unroll
      for (int p = 0; p < 2; ++p)
#pragma unroll
        for (int m = 0; m < MT; ++m)
          acc[m][g][p] = __builtin_amdgcn_mfma_f32_16x16x32_bf16(
              A[cur][m], B[cur][g][p], acc[m][g][p], 0, 0, 0);
  }
}

// Side GEMM at coupling steps: accs += root @ [U_iou|U_f], accw += x @ W_f.
__device__ __forceinline__ void gemm_side(
    const ushort* __restrict__ Wbu, const ushort* __restrict__ Wfx,
    const ushort* __restrict__ Rhb, const ushort* __restrict__ Axc,
    f32x4 (&accs)[4][2], f32x4 (&accw)[2], int w, int lane)
{
  const int col = lane & 15;
  const int kb  = (lane >> 4) * 16;
#pragma unroll
  for (int ks = 0; ks < 8; ++ks) {
    short8 ar = ldA(Rhb, col, ks * 64 + kb);
#pragma unroll
    for (int g = 0; g < 4; ++g)
#pragma unroll
      for (int p = 0; p < 2; ++p) {
        short8 b = *(const short8*)(Wbu + (((g * 16 + 2 * w + p) * 16 + 8 + ks) * 64 + lane) * 8);
        accs[g][p] = __builtin_amdgcn_mfma_f32_16x16x32_bf16(ar, b, accs[g][p], 0, 0, 0);
      }
    short8 ax = ldA(Axc, col, ks * 64 + kb);
#pragma unroll
    for (int p = 0; p < 2; ++p) {
      short8 b = *(const short8*)(Wfx + (((2 * w + p) * 8 + ks) * 64 + lane) * 8);
      accw[p] = __builtin_amdgcn_mfma_f32_16x16x32_bf16(ax, b, accw[p], 0, 0, 0);
    }
  }
}

#define ZACC(MT_, A_) { \
  _Pragma("unroll") for (int m_ = 0; m_ < MT_; ++m_) \
  _Pragma("unroll") for (int g_ = 0; g_ < 4; ++g_) \
  _Pragma("unroll") for (int p_ = 0; p_ < 2; ++p_) A_[m_][g_][p_] = zf4; }

__global__ __launch_bounds__(512, 2) void seq_kernel(
    const ushort* enc,                      // aliases td_h -> no __restrict__
    const ushort* __restrict__ Wbu, const ushort* __restrict__ Wtd,
    const ushort* __restrict__ Wfx,
    const float* __restrict__ b_iou, const float* __restrict__ b_f,
    const float* __restrict__ b_ih,  const float* __restrict__ b_hh,
    ushort* __restrict__ bu_h, ushort* td_h)
{
  __shared__ ushort Axb[2][32 * 256];       // x-tiles, double-buffered
  __shared__ ushort Ahb[2][32 * 256];       // h-tiles, double-buffered
  __shared__ ushort Rh[2][16 * 256];        // chain roots / td seeds

  const int tid  = threadIdx.x;
  const int lane = tid & 63;
  const int w    = tid >> 6;
  const int b0   = blockIdx.x * 16;
  const int col  = lane & 15;
  const int krow = lane >> 4;
  const f32x4 zf4 = {0.f, 0.f, 0.f, 0.f};
  const short8 zero8 = {0, 0, 0, 0, 0, 0, 0, 0};

  float bi0[2], bi1[2], bi2[2], bfv[2], bt0[2], bt1[2], bt2[2], bt3[2];
#pragma unroll
  for (int p = 0; p < 2; ++p) {
    int jj = (2 * w + p) * 16 + col;
    bi0[p] = b_iou[jj]; bi1[p] = b_iou[256 + jj]; bi2[p] = b_iou[512 + jj];
    bfv[p] = b_f[jj];
    bt0[p] = b_ih[jj]       + b_hh[jj];
    bt1[p] = b_ih[256 + jj] + b_hh[256 + jj];
    bt2[p] = b_ih[512 + jj] + b_hh[512 + jj];
    bt3[p] = b_ih[768 + jj] + b_hh[768 + jj];
  }

  float c2[2][2][4];                       // cell state per (Mtile, p, q)
  float rc0[2][4], rc1[2][4];              // bu-chain roots' c (static-indexed)
  float sc0[2][4], sc1[2][4];              // td seeds' c

  // stage: 16B chunk per (row, chk); fused = 2 chunks/thread, parent = 1.
#define STAGE32(V, DST) { \
  _Pragma("unroll") for (int h_ = 0; h_ < 2; ++h_) { \
    int cid_ = tid + h_ * 512; int rr_ = cid_ >> 5, ch_ = cid_ & 31; \
    int mt_ = rr_ >> 4, br_ = rr_ & 15; \
    long long rowg_ = ((long long)(b0 + br_) * NBv + (mt_ + 1)) * NVv + (V); \
    short8 xv_ = *(const short8*)(enc + rowg_ * 256 + ch_ * 8); \
    *(short8*)((char*)(DST) + ((rr_ * 512 + ch_ * 16) ^ ((rr_ & 7) << 4))) = xv_; } }

#define STAGE16(V, DST) { \
    int rr_ = tid >> 5, ch_ = tid & 31; \
    long long rowg_ = ((long long)(b0 + rr_) * NBv) * NVv + (V); \
    short8 xv_ = *(const short8*)(enc + rowg_ * 256 + ch_ * 8); \
    *(short8*)((char*)(DST) + ((rr_ * 512 + ch_ * 16) ^ ((rr_ & 7) << 4))) = xv_; }

#define STA(BUF, R, JJ, BITS) { \
    int off_ = ((R) * 512 + (JJ) * 2) ^ (((R) & 7) << 4); \
    (BUF)[off_ >> 1] = (BITS); }

  // ================= PHASE 1: fused bottom-up chains (v 39..0) ===============
  {
#pragma unroll
    for (int h_ = 0; h_ < 2; ++h_)
      *(short8*)((char*)Ahb[0] + (tid + h_ * 512) * 16) = zero8;
    STAGE32(CLEN - 1, Axb[0]);
#pragma unroll
    for (int m = 0; m < 2; ++m)
#pragma unroll
      for (int p = 0; p < 2; ++p)
#pragma unroll
        for (int q = 0; q < 4; ++q) c2[m][p][q] = 0.f;
    __syncthreads();
    for (int s = 0; s < CLEN; ++s) {
      const int v = CLEN - 1 - s, pp = s & 1;
      if (s < CLEN - 1) STAGE32(v - 1, Axb[pp ^ 1]);
      f32x4 acc[2][4][2]; ZACC(2, acc);
      gemm_main<2>(Wbu, Axb[pp], Ahb[pp], acc, w, lane);
#pragma unroll
      for (int m = 0; m < 2; ++m)
#pragma unroll
        for (int p = 0; p < 2; ++p) {
          const int jj = (2 * w + p) * 16 + col;
#pragma unroll
          for (int q = 0; q < 4; ++q) {
            const int br = krow * 4 + q;
            float I = acc[m][0][p][q] + bi0[p];
            float O = acc[m][1][p][q] + bi1[p];
            float U = acc[m][2][p][q] + bi2[p];
            float F = acc[m][3][p][q] + bfv[p];
            float cn = sigf(I) * tanh_f(U) + sigf(F) * c2[m][p][q];
            float hn = sigf(O) * tanh_f(cn);
            c2[m][p][q] = cn;
            ushort hb = f2bf(hn);
            STA(Ahb[pp ^ 1], m * 16 + br, jj, hb);
            long long rowg = ((long long)(b0 + br) * NBv + (m + 1)) * NVv + v;
            bu_h[rowg * 256 + jj] = hb;
            if (v == 0) {
              STA(Rh[m], br, jj, hb);
              if (m == 0) rc0[p][q] = cn; else rc1[p][q] = cn;
            }
          }
        }
      __syncthreads();
    }
  }

  // ================= PHASE 2: bottom-up parent chain (v 63..0) ===============
  {
    *(short8*)((char*)Ahb[0] + tid * 16) = zero8;     // rows 0..15
    STAGE16(NVv - 1, Axb[0]);
#pragma unroll
    for (int p = 0; p < 2; ++p)
#pragma unroll
      for (int q = 0; q < 4; ++q) c2[0][p][q] = 0.f;
    __syncthreads();
    for (int s = 0; s < NVv; ++s) {
      const int v = NVv - 1 - s, pp = s & 1;
      if (s < NVv - 1) STAGE16(v - 1, Axb[pp ^ 1]);
      f32x4 acc[1][4][2]; ZACC(1, acc);
      gemm_main<1>(Wbu, Axb[pp], Ahb[pp], acc, w, lane);
      const int ck = (v == CI0) ? 0 : ((v == CI1) ? 1 : -1);
      f32x4 accs[4][2]; f32x4 accw[2];
      if (ck >= 0) {
#pragma unroll
        for (int g = 0; g < 4; ++g)
#pragma unroll
          for (int p = 0; p < 2; ++p) accs[g][p] = zf4;
        accw[0] = zf4; accw[1] = zf4;
        const ushort* Rp = (ck == 0) ? Rh[0] : Rh[1];
        gemm_side(Wbu, Wfx, Rp, Axb[pp], accs, accw, w, lane);
      }
#pragma unroll
      for (int p = 0; p < 2; ++p) {
        const int jj = (2 * w + p) * 16 + col;
#pragma unroll
        for (int q = 0; q < 4; ++q) {
          const int br = krow * 4 + q;
          float I  = acc[0][0][p][q] + bi0[p];
          float O  = acc[0][1][p][q] + bi1[p];
          float U  = acc[0][2][p][q] + bi2[p];
          float F1 = acc[0][3][p][q] + bfv[p];
          float fc = sigf(F1) * c2[0][p][q];
          if (ck >= 0) {
            I += accs[0][p][q]; O += accs[1][p][q]; U += accs[2][p][q];
            float wfx = accw[p][q] + bfv[p];
            float rcv = (ck == 0) ? rc0[p][q] : rc1[p][q];
            fc += sigf(wfx + accs[3][p][q]) * rcv;
          }
          float cn = sigf(I) * tanh_f(U) + fc;
          float hn = sigf(O) * tanh_f(cn);
          c2[0][p][q] = cn;
          ushort hb = f2bf(hn);
          STA(Ahb[pp ^ 1], br, jj, hb);
          long long rowg = ((long long)(b0 + br) * NBv) * NVv + v;
          bu_h[rowg * 256 + jj] = hb;
          if (v == 0) td_h[rowg * 256 + jj] = hb;    // td seed
        }
      }
      __syncthreads();
    }
  }
  // NB: phase 2 has 64 steps -> its last epilogue wrote Ahb[0]; c2[0] carries.

  // ================= PHASE 3: top-down parent chain (v 1..63) ================
  {
    STAGE16(1, Axb[0]);
    __syncthreads();
    for (int s = 0; s < NVv - 1; ++s) {
      const int v = 1 + s, pp = s & 1;
      if (s < NVv - 2) STAGE16(v + 1, Axb[pp ^ 1]);
      f32x4 acc[1][4][2]; ZACC(1, acc);
      gemm_main<1>(Wtd, Axb[pp], Ahb[pp], acc, w, lane);
#pragma unroll
      for (int p = 0; p < 2; ++p) {
        const int jj = (2 * w + p) * 16 + col;
#pragma unroll
        for (int q = 0; q < 4; ++q) {
          const int br = krow * 4 + q;
          float I = acc[0][0][p][q] + bt0[p];
          float F = acc[0][1][p][q] + bt1[p];
          float G = acc[0][2][p][q] + bt2[p];
          float O = acc[0][3][p][q] + bt3[p];
          float cn = sigf(F) * c2[0][p][q] + sigf(I) * tanh_f(G);
          float hn = sigf(O) * tanh_f(cn);
          c2[0][p][q] = cn;
          ushort hb = f2bf(hn);
          STA(Ahb[pp ^ 1], br, jj, hb);
          long long rowg = ((long long)(b0 + br) * NBv) * NVv + v;
          td_h[rowg * 256 + jj] = hb;
          if (v == CI0) { STA(Rh[0], br, jj, hb); sc0[p][q] = cn; }
          if (v == CI1) { STA(Rh[1], br, jj, hb); sc1[p][q] = cn; }
        }
      }
      __syncthreads();
    }
  }

  // ================= PHASE 4: fused top-down chains (v 0..39) ================
  {
#pragma unroll
    for (int h_ = 0; h_ < 2; ++h_) {
      int cid_ = tid + h_ * 512; int rr_ = cid_ >> 5, ch_ = cid_ & 31;
      int mt_ = rr_ >> 4, br_ = rr_ & 15;
      short8 vv = *(const short8*)((const char*)Rh[mt_] +
                    ((br_ * 512 + ch_ * 16) ^ ((br_ & 7) << 4)));
      *(short8*)((char*)Ahb[0] + ((rr_ * 512 + ch_ * 16) ^ ((rr_ & 7) << 4))) = vv;
    }
    STAGE32(0, Axb[0]);
#pragma unroll
    for (int m = 0; m < 2; ++m)
#pragma unroll
      for (int p = 0; p < 2; ++p)
#pragma unroll
        for (int q = 0; q < 4; ++q)
          c2[m][p][q] = (m == 0) ? sc0[p][q] : sc1[p][q];
    __syncthreads();
    for (int s = 0; s < CLEN; ++s) {
      const int v = s, pp = s & 1;
      if (s < CLEN - 1) STAGE32(v + 1, Axb[pp ^ 1]);
      f32x4 acc[2][4][2]; ZACC(2, acc);
      gemm_main<2>(Wtd, Axb[pp], Ahb[pp], acc, w, lane);
#pragma unroll
      for (int m = 0; m < 2; ++m)
#pragma unroll
        for (int p = 0; p < 2; ++p) {
          const int jj = (2 * w + p) * 16 + col;
#pragma unroll
          for (int q = 0; q < 4; ++q) {
            const int br = krow * 4 + q;
            float I = acc[m][0][p][q] + bt0[p];
            float F = acc[m][1][p][q] + bt1[p];
            float G = acc[m][2][p][q] + bt2[p];
            float O = acc[m][3][p][q] + bt3[p];
            float cn = sigf(F) * c2[m][p][q] + sigf(I) * tanh_f(G);
            float hn = sigf(O) * tanh_f(cn);
            c2[m][p][q] = cn;
            ushort hb = f2bf(hn);
            STA(Ahb[pp ^ 1], m * 16 + br, jj, hb);
            long long rowg = ((long long)(b0 + br) * NBv + (m + 1)) * NVv + v;
            td_h[rowg * 256 + jj] = hb;
          }
        }
      __syncthreads();
    }
  }
}

// ================= decoder (round-2, known-good) ==============================
__global__ __launch_bounds__(256) void dec_kernel(
    const bf16* __restrict__ bu_h, const bf16* __restrict__ td_h,
    const float* __restrict__ cv,
    const float* __restrict__ w1, const float* __restrict__ b1,
    const float* __restrict__ w2, const float* __restrict__ b2,
    float* __restrict__ out)
{
  __shared__ float comb[8][2 * Hd];
  __shared__ float hid[8][Hd];
  __shared__ float red[4][3];
  long long row0 = (long long)blockIdx.x * 8;
  int j = threadIdx.x;
#pragma unroll
  for (int r = 0; r < 8; r++) {
    comb[r][j]      = __bfloat162float(bu_h[(row0 + r) * Hd + j]);
    comb[r][Hd + j] = __bfloat162float(td_h[(row0 + r) * Hd + j]);
  }
  __syncthreads();
  float acc[8];
  float bb = b1[j];
#pragma unroll
  for (int r = 0; r < 8; r++) acc[r] = bb;
  for (int t = 0; t < 2 * Hd; t++) {
    float w = w1[t * Hd + j];
#pragma unroll
    for (int r = 0; r < 8; r++) acc[r] += comb[r][t] * w;
  }
#pragma unroll
  for (int r = 0; r < 8; r++) hid[r][j] = fmaxf(acc[r], 0.f);
  __syncthreads();

  float w20 = w2[j * 3 + 0], w21 = w2[j * 3 + 1], w22 = w2[j * 3 + 2];
  int wid = j >> 6, lane = j & 63;
  for (int r = 0; r < 8; r++) {
    float h = hid[r][j];
    float p0 = h * w20, p1 = h * w21, p2 = h * w22;
#pragma unroll
    for (int off = 32; off > 0; off >>= 1) {
      p0 += __shfl_down(p0, off);
      p1 += __shfl_down(p1, off);
      p2 += __shfl_down(p2, off);
    }
    if (lane == 0) { red[wid][0] = p0; red[wid][1] = p1; red[wid][2] = p2; }
    __syncthreads();
    if (j < 3) {
      long long row = row0 + r;
      int v  = (int)(row % NVv);
      int br = (int)((row / NVv) % NBv);
      float res = 0.f;
      if (br == 0 || v < CLEN) {
        float s = red[0][j] + red[1][j] + red[2][j] + red[3][j];
        res = cv[row * 3 + j] + s + b2[j];
      }
      out[row * 3 + j] = res;
    }
    __syncthreads();
  }
}

extern "C" void kernel_launch(void* const* d_in, const int* in_sizes, int n_in,
                              void* d_out, int out_size, void* d_ws, size_t ws_size,
                              hipStream_t stream) {
  const float* cv     = (const float*)d_in[0];
  const float* pv     = (const float*)d_in[1];
  const float* hints  = (const float*)d_in[2];
  const float* enc_w1 = (const float*)d_in[3];
  const float* enc_b1 = (const float*)d_in[4];
  const float* enc_w2 = (const float*)d_in[5];
  const float* enc_b2 = (const float*)d_in[6];
  const float* W_iou  = (const float*)d_in[7];
  const float* b_iou  = (const float*)d_in[8];
  const float* U_iou  = (const float*)d_in[9];
  const float* W_f    = (const float*)d_in[10];
  const float* b_f    = (const float*)d_in[11];
  const float* U_f    = (const float*)d_in[12];
  const float* W_ih   = (const float*)d_in[13];
  const float* b_ih   = (const float*)d_in[14];
  const float* W_hh   = (const float*)d_in[15];
  const float* b_hh   = (const float*)d_in[16];
  const float* dec_w1 = (const float*)d_in[17];
  const float* dec_b1 = (const float*)d_in[18];
  const float* dec_w2 = (const float*)d_in[19];
  const float* dec_b2 = (const float*)d_in[20];

  size_t act = (size_t)NROWS * 256;
  size_t need = (2 * act + 2 * (size_t)(512 * 1024) + 256 * 256) * sizeof(ushort);
  if (ws_size < need) return;

  ushort* encW = (ushort*)d_ws;         // enc, overwritten in place as td_h
  ushort* buh  = encW + act;
  ushort* Wbu  = buh + act;
  ushort* Wtd  = Wbu + 512 * 1024;
  ushort* Wfx  = Wtd + 512 * 1024;

  pack_bu_kernel<<<2048, 256, 0, stream>>>(W_iou, W_f, U_iou, U_f, Wbu);
  pack_td_kernel<<<2048, 256, 0, stream>>>(W_ih, W_hh, Wtd);
  pack_wfx_kernel<<<256, 256, 0, stream>>>(W_f, Wfx);

  enc_kernel<<<(int)(NROWS / 8), 256, 0, stream>>>(cv, pv, hints, enc_w1, enc_b1,
                                                   enc_w2, enc_b2, (bf16*)encW);
  seq_kernel<<<BATCH / 16, 512, 0, stream>>>(encW, Wbu, Wtd, Wfx, b_iou, b_f,
                                             b_ih, b_hh, buh, encW);
  dec_kernel<<<(int)(NROWS / 8), 256, 0, stream>>>((const bf16*)buh, (const bf16*)encW,
                                                   cv, dec_w1, dec_b1, dec_w2, dec_b2,
                                                   (float*)d_out);
}

// Round 5
// 4189.915 us; speedup vs baseline: 1.6730x; 1.6730x over previous
//
#include <hip/hip_runtime.h>
#include <hip/hip_bf16.h>

// BDLOTreeLSTM on MI355X — round 5: round-4 fused schedule (M=32, one
// barrier/step, dbuf LDS A-tiles) WITHOUT the register B-ring (it spilled:
// FETCH 50->385MB). B fragments loaded inline just-in-time, as in round 3.

constexpr int Hd    = 256;
constexpr int NBv   = 3;
constexpr int NVv   = 64;
constexpr int BATCH = 512;
constexpr long long NROWS = (long long)BATCH * NBv * NVv;   // 98304
constexpr int CLEN = 40;
constexpr int CI0 = 16, CI1 = 48;

typedef __hip_bfloat16 bf16;
typedef unsigned short ushort;
typedef __attribute__((ext_vector_type(8))) short short8;
typedef __attribute__((ext_vector_type(4))) float f32x4;

__device__ __forceinline__ float sigf(float x)   { return 1.f / (1.f + __expf(-x)); }
__device__ __forceinline__ float tanh_f(float x) { return 1.f - 2.f / (__expf(2.f * x) + 1.f); }

__device__ __forceinline__ ushort f2bf(float x) {
  unsigned u = __float_as_uint(x);
  return (ushort)((u + 0x7FFFu + ((u >> 16) & 1u)) >> 16);   // RNE
}

// ================= weight packing (round-3, verified) =========================
__global__ __launch_bounds__(256) void pack_bu_kernel(
    const float* __restrict__ W_iou, const float* __restrict__ W_f,
    const float* __restrict__ U_iou, const float* __restrict__ U_f,
    ushort* __restrict__ out)   // [512 K][1024 N]: [[W_iou|W_f];[U_iou|U_f]]
{
  int idx = blockIdx.x * 256 + threadIdx.x;
  int j = idx & 7, l = (idx >> 3) & 63, T = idx >> 9;
  int ks = T & 15, nt = T >> 4;
  int k = ks * 32 + (l >> 4) * 8 + j;
  int n = nt * 16 + (l & 15);
  float v;
  if (k < 256) v = (n < 768) ? W_iou[k * 768 + n] : W_f[k * 256 + (n - 768)];
  else         v = (n < 768) ? U_iou[(k - 256) * 768 + n] : U_f[(k - 256) * 256 + (n - 768)];
  out[idx] = f2bf(v);
}

__global__ __launch_bounds__(256) void pack_td_kernel(
    const float* __restrict__ W_ih, const float* __restrict__ W_hh,
    ushort* __restrict__ out)   // [512][1024]: [[W_ih];[W_hh]]
{
  int idx = blockIdx.x * 256 + threadIdx.x;
  int j = idx & 7, l = (idx >> 3) & 63, T = idx >> 9;
  int ks = T & 15, nt = T >> 4;
  int k = ks * 32 + (l >> 4) * 8 + j;
  int n = nt * 16 + (l & 15);
  float v = (k < 256) ? W_ih[k * 1024 + n] : W_hh[(k - 256) * 1024 + n];
  out[idx] = f2bf(v);
}

__global__ __launch_bounds__(256) void pack_wfx_kernel(
    const float* __restrict__ W_f, ushort* __restrict__ out)   // [256][256]
{
  int idx = blockIdx.x * 256 + threadIdx.x;
  int j = idx & 7, l = (idx >> 3) & 63, T = idx >> 9;
  int ks = T & 7, nt = T >> 3;
  int k = ks * 32 + (l >> 4) * 8 + j;
  int n = nt * 16 + (l & 15);
  out[idx] = f2bf(W_f[k * 256 + n]);
}

// ================= fused encoder (round-2, known-good) ========================
__global__ __launch_bounds__(256) void enc_kernel(
    const float* __restrict__ cv, const float* __restrict__ pv,
    const float* __restrict__ hints,
    const float* __restrict__ w1, const float* __restrict__ b1,
    const float* __restrict__ w2, const float* __restrict__ b2,
    bf16* __restrict__ enc)
{
  __shared__ float fs[8][9];
  __shared__ float h1s[8][Hd];
  long long row0 = (long long)blockIdx.x * 8;
  int tid = threadIdx.x;
  if (tid < 72) {
    int r = tid / 9, i = tid % 9;
    long long row = row0 + r;
    float v;
    if (i < 3)      v = cv[row * 3 + i];
    else if (i < 6) v = cv[row * 3 + (i - 3)] - pv[row * 3 + (i - 3)];
    else            v = hints[row * 3 + (i - 6)];
    fs[r][i] = v;
  }
  __syncthreads();
  int j = tid;
  {
    float w[9];
#pragma unroll
    for (int i = 0; i < 9; i++) w[i] = w1[i * Hd + j];
    float bb = b1[j];
#pragma unroll
    for (int r = 0; r < 8; r++) {
      float a = bb;
#pragma unroll
      for (int i = 0; i < 9; i++) a += fs[r][i] * w[i];
      h1s[r][j] = fmaxf(a, 0.f);
    }
  }
  __syncthreads();
  float acc[8];
  float bb2 = b2[j];
#pragma unroll
  for (int r = 0; r < 8; r++) acc[r] = bb2;
  for (int t = 0; t < Hd; t++) {
    float w = w2[t * Hd + j];
#pragma unroll
    for (int r = 0; r < 8; r++) acc[r] += h1s[r][t] * w;
  }
#pragma unroll
  for (int r = 0; r < 8; r++) enc[(row0 + r) * Hd + j] = __float2bfloat16(acc[r]);
}

// ================= seq kernel helpers =========================================
__device__ __forceinline__ short8 ldA(const ushort* buf, int row, int kbyte) {
  int off = (row * 512 + kbyte) ^ ((row & 7) << 4);
  return *(const short8*)((const char*)buf + off);
}

// Main GEMM: A [MT*16 x 512] = [Ax | Ah], B = W (frag-packed), N-slice per wave.
// B loads inline (round-3 style): no persistent B registers -> no spills.
template<int MT>
__device__ __forceinline__ void gemm_main(
    const ushort* __restrict__ W, const ushort* __restrict__ Axb_,
    const ushort* __restrict__ Ahb_, f32x4 (&acc)[MT][4][2],
    int w, int lane)
{
  const int col = lane & 15;
  const int kb  = (lane >> 4) * 16;
#pragma unroll 4
  for (int ks = 0; ks < 16; ++ks) {
    const ushort* Ab = (ks < 8) ? Axb_ : Ahb_;
    const int kk = ks & 7;
    short8 A[MT];
#pragma unroll
    for (int m = 0; m < MT; ++m)
      A[m] = ldA(Ab, m * 16 + col, kk * 64 + kb);
#pragma unroll
    for (int g = 0; g < 4; ++g)
#pragma unroll
      for (int p = 0; p < 2; ++p) {
        short8 b = *(const short8*)(W + (((long long)(g * 16 + 2 * w + p) * 16 + ks) * 64 + lane) * 8);
#pragma unroll
        for (int m = 0; m < MT; ++m)
          acc[m][g][p] = __builtin_amdgcn_mfma_f32_16x16x32_bf16(
              A[m], b, acc[m][g][p], 0, 0, 0);
      }
  }
}

// Side GEMM at coupling steps: accs += root @ [U_iou|U_f], accw += x @ W_f.
__device__ __forceinline__ void gemm_side(
    const ushort* __restrict__ Wbu, const ushort* __restrict__ Wfx,
    const ushort* __restrict__ Rhb, const ushort* __restrict__ Axc,
    f32x4 (&accs)[4][2], f32x4 (&accw)[2], int w, int lane)
{
  const int col = lane & 15;
  const int kb  = (lane >> 4) * 16;
#pragma unroll
  for (int ks = 0; ks < 8; ++ks) {
    short8 ar = ldA(Rhb, col, ks * 64 + kb);
#pragma unroll
    for (int g = 0; g < 4; ++g)
#pragma unroll
      for (int p = 0; p < 2; ++p) {
        short8 b = *(const short8*)(Wbu + (((g * 16 + 2 * w + p) * 16 + 8 + ks) * 64 + lane) * 8);
        accs[g][p] = __builtin_amdgcn_mfma_f32_16x16x32_bf16(ar, b, accs[g][p], 0, 0, 0);
      }
    short8 ax = ldA(Axc, col, ks * 64 + kb);
#pragma unroll
    for (int p = 0; p < 2; ++p) {
      short8 b = *(const short8*)(Wfx + (((2 * w + p) * 8 + ks) * 64 + lane) * 8);
      accw[p] = __builtin_amdgcn_mfma_f32_16x16x32_bf16(ax, b, accw[p], 0, 0, 0);
    }
  }
}

#define ZACC(MT_, A_) { \
  _Pragma("unroll") for (int m_ = 0; m_ < MT_; ++m_) \
  _Pragma("unroll") for (int g_ = 0; g_ < 4; ++g_) \
  _Pragma("unroll") for (int p_ = 0; p_ < 2; ++p_) A_[m_][g_][p_] = zf4; }

__global__ __launch_bounds__(512, 2) void seq_kernel(
    const ushort* enc,                      // aliases td_h -> no __restrict__
    const ushort* __restrict__ Wbu, const ushort* __restrict__ Wtd,
    const ushort* __restrict__ Wfx,
    const float* __restrict__ b_iou, const float* __restrict__ b_f,
    const float* __restrict__ b_ih,  const float* __restrict__ b_hh,
    ushort* __restrict__ bu_h, ushort* td_h)
{
  __shared__ ushort Axb[2][32 * 256];       // x-tiles, double-buffered
  __shared__ ushort Ahb[2][32 * 256];       // h-tiles, double-buffered
  __shared__ ushort Rh[2][16 * 256];        // chain roots / td seeds

  const int tid  = threadIdx.x;
  const int lane = tid & 63;
  const int w    = tid >> 6;
  const int b0   = blockIdx.x * 16;
  const int col  = lane & 15;
  const int krow = lane >> 4;
  const f32x4 zf4 = {0.f, 0.f, 0.f, 0.f};
  const short8 zero8 = {0, 0, 0, 0, 0, 0, 0, 0};

  float bi0[2], bi1[2], bi2[2], bfv[2], bt0[2], bt1[2], bt2[2], bt3[2];
#pragma unroll
  for (int p = 0; p < 2; ++p) {
    int jj = (2 * w + p) * 16 + col;
    bi0[p] = b_iou[jj]; bi1[p] = b_iou[256 + jj]; bi2[p] = b_iou[512 + jj];
    bfv[p] = b_f[jj];
    bt0[p] = b_ih[jj]       + b_hh[jj];
    bt1[p] = b_ih[256 + jj] + b_hh[256 + jj];
    bt2[p] = b_ih[512 + jj] + b_hh[512 + jj];
    bt3[p] = b_ih[768 + jj] + b_hh[768 + jj];
  }

  float c2[2][2][4];                       // cell state per (Mtile, p, q)
  float rc0[2][4], rc1[2][4];              // bu-chain roots' c (static-indexed)
  float sc0[2][4], sc1[2][4];              // td seeds' c

#define STAGE32(V, DST) { \
  _Pragma("unroll") for (int h_ = 0; h_ < 2; ++h_) { \
    int cid_ = tid + h_ * 512; int rr_ = cid_ >> 5, ch_ = cid_ & 31; \
    int mt_ = rr_ >> 4, br_ = rr_ & 15; \
    long long rowg_ = ((long long)(b0 + br_) * NBv + (mt_ + 1)) * NVv + (V); \
    short8 xv_ = *(const short8*)(enc + rowg_ * 256 + ch_ * 8); \
    *(short8*)((char*)(DST) + ((rr_ * 512 + ch_ * 16) ^ ((rr_ & 7) << 4))) = xv_; } }

#define STAGE16(V, DST) { \
    int rr_ = tid >> 5, ch_ = tid & 31; \
    long long rowg_ = ((long long)(b0 + rr_) * NBv) * NVv + (V); \
    short8 xv_ = *(const short8*)(enc + rowg_ * 256 + ch_ * 8); \
    *(short8*)((char*)(DST) + ((rr_ * 512 + ch_ * 16) ^ ((rr_ & 7) << 4))) = xv_; }

#define STA(BUF, R, JJ, BITS) { \
    int off_ = ((R) * 512 + (JJ) * 2) ^ (((R) & 7) << 4); \
    (BUF)[off_ >> 1] = (BITS); }

  // ================= PHASE 1: fused bottom-up chains (v 39..0) ===============
  {
#pragma unroll
    for (int h_ = 0; h_ < 2; ++h_)
      *(short8*)((char*)Ahb[0] + (tid + h_ * 512) * 16) = zero8;
    STAGE32(CLEN - 1, Axb[0]);
#pragma unroll
    for (int m = 0; m < 2; ++m)
#pragma unroll
      for (int p = 0; p < 2; ++p)
#pragma unroll
        for (int q = 0; q < 4; ++q) c2[m][p][q] = 0.f;
    __syncthreads();
    for (int s = 0; s < CLEN; ++s) {
      const int v = CLEN - 1 - s, pp = s & 1;
      if (s < CLEN - 1) STAGE32(v - 1, Axb[pp ^ 1]);
      f32x4 acc[2][4][2]; ZACC(2, acc);
      gemm_main<2>(Wbu, Axb[pp], Ahb[pp], acc, w, lane);
#pragma unroll
      for (int m = 0; m < 2; ++m)
#pragma unroll
        for (int p = 0; p < 2; ++p) {
          const int jj = (2 * w + p) * 16 + col;
#pragma unroll
          for (int q = 0; q < 4; ++q) {
            const int br = krow * 4 + q;
            float I = acc[m][0][p][q] + bi0[p];
            float O = acc[m][1][p][q] + bi1[p];
            float U = acc[m][2][p][q] + bi2[p];
            float F = acc[m][3][p][q] + bfv[p];
            float cn = sigf(I) * tanh_f(U) + sigf(F) * c2[m][p][q];
            float hn = sigf(O) * tanh_f(cn);
            c2[m][p][q] = cn;
            ushort hb = f2bf(hn);
            STA(Ahb[pp ^ 1], m * 16 + br, jj, hb);
            long long rowg = ((long long)(b0 + br) * NBv + (m + 1)) * NVv + v;
            bu_h[rowg * 256 + jj] = hb;
            if (v == 0) {
              STA(Rh[m], br, jj, hb);
              if (m == 0) rc0[p][q] = cn; else rc1[p][q] = cn;
            }
          }
        }
      __syncthreads();
    }
  }

  // ================= PHASE 2: bottom-up parent chain (v 63..0) ===============
  {
    *(short8*)((char*)Ahb[0] + tid * 16) = zero8;     // rows 0..15
    STAGE16(NVv - 1, Axb[0]);
#pragma unroll
    for (int p = 0; p < 2; ++p)
#pragma unroll
      for (int q = 0; q < 4; ++q) c2[0][p][q] = 0.f;
    __syncthreads();
    for (int s = 0; s < NVv; ++s) {
      const int v = NVv - 1 - s, pp = s & 1;
      if (s < NVv - 1) STAGE16(v - 1, Axb[pp ^ 1]);
      f32x4 acc[1][4][2]; ZACC(1, acc);
      gemm_main<1>(Wbu, Axb[pp], Ahb[pp], acc, w, lane);
      const int ck = (v == CI0) ? 0 : ((v == CI1) ? 1 : -1);
      f32x4 accs[4][2]; f32x4 accw[2];
      if (ck >= 0) {
#pragma unroll
        for (int g = 0; g < 4; ++g)
#pragma unroll
          for (int p = 0; p < 2; ++p) accs[g][p] = zf4;
        accw[0] = zf4; accw[1] = zf4;
        const ushort* Rp = (ck == 0) ? Rh[0] : Rh[1];
        gemm_side(Wbu, Wfx, Rp, Axb[pp], accs, accw, w, lane);
      }
#pragma unroll
      for (int p = 0; p < 2; ++p) {
        const int jj = (2 * w + p) * 16 + col;
#pragma unroll
        for (int q = 0; q < 4; ++q) {
          const int br = krow * 4 + q;
          float I  = acc[0][0][p][q] + bi0[p];
          float O  = acc[0][1][p][q] + bi1[p];
          float U  = acc[0][2][p][q] + bi2[p];
          float F1 = acc[0][3][p][q] + bfv[p];
          float fc = sigf(F1) * c2[0][p][q];
          if (ck >= 0) {
            I += accs[0][p][q]; O += accs[1][p][q]; U += accs[2][p][q];
            float wfx = accw[p][q] + bfv[p];
            float rcv = (ck == 0) ? rc0[p][q] : rc1[p][q];
            fc += sigf(wfx + accs[3][p][q]) * rcv;
          }
          float cn = sigf(I) * tanh_f(U) + fc;
          float hn = sigf(O) * tanh_f(cn);
          c2[0][p][q] = cn;
          ushort hb = f2bf(hn);
          STA(Ahb[pp ^ 1], br, jj, hb);
          long long rowg = ((long long)(b0 + br) * NBv) * NVv + v;
          bu_h[rowg * 256 + jj] = hb;
          if (v == 0) td_h[rowg * 256 + jj] = hb;    // td seed
        }
      }
      __syncthreads();
    }
  }
  // NB: phase 2 has 64 steps -> last epilogue wrote Ahb[0]; c2[0] carries.

  // ================= PHASE 3: top-down parent chain (v 1..63) ================
  {
    STAGE16(1, Axb[0]);
    __syncthreads();
    for (int s = 0; s < NVv - 1; ++s) {
      const int v = 1 + s, pp = s & 1;
      if (s < NVv - 2) STAGE16(v + 1, Axb[pp ^ 1]);
      f32x4 acc[1][4][2]; ZACC(1, acc);
      gemm_main<1>(Wtd, Axb[pp], Ahb[pp], acc, w, lane);
#pragma unroll
      for (int p = 0; p < 2; ++p) {
        const int jj = (2 * w + p) * 16 + col;
#pragma unroll
        for (int q = 0; q < 4; ++q) {
          const int br = krow * 4 + q;
          float I = acc[0][0][p][q] + bt0[p];
          float F = acc[0][1][p][q] + bt1[p];
          float G = acc[0][2][p][q] + bt2[p];
          float O = acc[0][3][p][q] + bt3[p];
          float cn = sigf(F) * c2[0][p][q] + sigf(I) * tanh_f(G);
          float hn = sigf(O) * tanh_f(cn);
          c2[0][p][q] = cn;
          ushort hb = f2bf(hn);
          STA(Ahb[pp ^ 1], br, jj, hb);
          long long rowg = ((long long)(b0 + br) * NBv) * NVv + v;
          td_h[rowg * 256 + jj] = hb;
          if (v == CI0) { STA(Rh[0], br, jj, hb); sc0[p][q] = cn; }
          if (v == CI1) { STA(Rh[1], br, jj, hb); sc1[p][q] = cn; }
        }
      }
      __syncthreads();
    }
  }

  // ================= PHASE 4: fused top-down chains (v 0..39) ================
  {
#pragma unroll
    for (int h_ = 0; h_ < 2; ++h_) {
      int cid_ = tid + h_ * 512; int rr_ = cid_ >> 5, ch_ = cid_ & 31;
      int mt_ = rr_ >> 4, br_ = rr_ & 15;
      short8 vv = *(const short8*)((const char*)Rh[mt_] +
                    ((br_ * 512 + ch_ * 16) ^ ((br_ & 7) << 4)));
      *(short8*)((char*)Ahb[0] + ((rr_ * 512 + ch_ * 16) ^ ((rr_ & 7) << 4))) = vv;
    }
    STAGE32(0, Axb[0]);
#pragma unroll
    for (int m = 0; m < 2; ++m)
#pragma unroll
      for (int p = 0; p < 2; ++p)
#pragma unroll
        for (int q = 0; q < 4; ++q)
          c2[m][p][q] = (m == 0) ? sc0[p][q] : sc1[p][q];
    __syncthreads();
    for (int s = 0; s < CLEN; ++s) {
      const int v = s, pp = s & 1;
      if (s < CLEN - 1) STAGE32(v + 1, Axb[pp ^ 1]);
      f32x4 acc[2][4][2]; ZACC(2, acc);
      gemm_main<2>(Wtd, Axb[pp], Ahb[pp], acc, w, lane);
#pragma unroll
      for (int m = 0; m < 2; ++m)
#pragma unroll
        for (int p = 0; p < 2; ++p) {
          const int jj = (2 * w + p) * 16 + col;
#pragma unroll
          for (int q = 0; q < 4; ++q) {
            const int br = krow * 4 + q;
            float I = acc[m][0][p][q] + bt0[p];
            float F = acc[m][1][p][q] + bt1[p];
            float G = acc[m][2][p][q] + bt2[p];
            float O = acc[m][3][p][q] + bt3[p];
            float cn = sigf(F) * c2[m][p][q] + sigf(I) * tanh_f(G);
            float hn = sigf(O) * tanh_f(cn);
            c2[m][p][q] = cn;
            ushort hb = f2bf(hn);
            STA(Ahb[pp ^ 1], m * 16 + br, jj, hb);
            long long rowg = ((long long)(b0 + br) * NBv + (m + 1)) * NVv + v;
            td_h[rowg * 256 + jj] = hb;
          }
        }
      __syncthreads();
    }
  }
}

// ================= decoder (round-2, known-good) ==============================
__global__ __launch_bounds__(256) void dec_kernel(
    const bf16* __restrict__ bu_h, const bf16* __restrict__ td_h,
    const float* __restrict__ cv,
    const float* __restrict__ w1, const float* __restrict__ b1,
    const float* __restrict__ w2, const float* __restrict__ b2,
    float* __restrict__ out)
{
  __shared__ float comb[8][2 * Hd];
  __shared__ float hid[8][Hd];
  __shared__ float red[4][3];
  long long row0 = (long long)blockIdx.x * 8;
  int j = threadIdx.x;
#pragma unroll
  for (int r = 0; r < 8; r++) {
    comb[r][j]      = __bfloat162float(bu_h[(row0 + r) * Hd + j]);
    comb[r][Hd + j] = __bfloat162float(td_h[(row0 + r) * Hd + j]);
  }
  __syncthreads();
  float acc[8];
  float bb = b1[j];
#pragma unroll
  for (int r = 0; r < 8; r++) acc[r] = bb;
  for (int t = 0; t < 2 * Hd; t++) {
    float w = w1[t * Hd + j];
#pragma unroll
    for (int r = 0; r < 8; r++) acc[r] += comb[r][t] * w;
  }
#pragma unroll
  for (int r = 0; r < 8; r++) hid[r][j] = fmaxf(acc[r], 0.f);
  __syncthreads();

  float w20 = w2[j * 3 + 0], w21 = w2[j * 3 + 1], w22 = w2[j * 3 + 2];
  int wid = j >> 6, lane = j & 63;
  for (int r = 0; r < 8; r++) {
    float h = hid[r][j];
    float p0 = h * w20, p1 = h * w21, p2 = h * w22;
#pragma unroll
    for (int off = 32; off > 0; off >>= 1) {
      p0 += __shfl_down(p0, off);
      p1 += __shfl_down(p1, off);
      p2 += __shfl_down(p2, off);
    }
    if (lane == 0) { red[wid][0] = p0; red[wid][1] = p1; red[wid][2] = p2; }
    __syncthreads();
    if (j < 3) {
      long long row = row0 + r;
      int v  = (int)(row % NVv);
      int br = (int)((row / NVv) % NBv);
      float res = 0.f;
      if (br == 0 || v < CLEN) {
        float s = red[0][j] + red[1][j] + red[2][j] + red[3][j];
        res = cv[row * 3 + j] + s + b2[j];
      }
      out[row * 3 + j] = res;
    }
    __syncthreads();
  }
}

extern "C" void kernel_launch(void* const* d_in, const int* in_sizes, int n_in,
                              void* d_out, int out_size, void* d_ws, size_t ws_size,
                              hipStream_t stream) {
  const float* cv     = (const float*)d_in[0];
  const float* pv     = (const float*)d_in[1];
  const float* hints  = (const float*)d_in[2];
  const float* enc_w1 = (const float*)d_in[3];
  const float* enc_b1 = (const float*)d_in[4];
  const float* enc_w2 = (const float*)d_in[5];
  const float* enc_b2 = (const float*)d_in[6];
  const float* W_iou  = (const float*)d_in[7];
  const float* b_iou  = (const float*)d_in[8];
  const float* U_iou  = (const float*)d_in[9];
  const float* W_f    = (const float*)d_in[10];
  const float* b_f    = (const float*)d_in[11];
  const float* U_f    = (const float*)d_in[12];
  const float* W_ih   = (const float*)d_in[13];
  const float* b_ih   = (const float*)d_in[14];
  const float* W_hh   = (const float*)d_in[15];
  const float* b_hh   = (const float*)d_in[16];
  const float* dec_w1 = (const float*)d_in[17];
  const float* dec_b1 = (const float*)d_in[18];
  const float* dec_w2 = (const float*)d_in[19];
  const float* dec_b2 = (const float*)d_in[20];

  size_t act = (size_t)NROWS * 256;
  size_t need = (2 * act + 2 * (size_t)(512 * 1024) + 256 * 256) * sizeof(ushort);
  if (ws_size < need) return;

  ushort* encW = (ushort*)d_ws;         // enc, overwritten in place as td_h
  ushort* buh  = encW + act;
  ushort* Wbu  = buh + act;
  ushort* Wtd  = Wbu + 512 * 1024;
  ushort* Wfx  = Wtd + 512 * 1024;

  pack_bu_kernel<<<2048, 256, 0, stream>>>(W_iou, W_f, U_iou, U_f, Wbu);
  pack_td_kernel<<<2048, 256, 0, stream>>>(W_ih, W_hh, Wtd);
  pack_wfx_kernel<<<256, 256, 0, stream>>>(W_f, Wfx);

  enc_kernel<<<(int)(NROWS / 8), 256, 0, stream>>>(cv, pv, hints, enc_w1, enc_b1,
                                                   enc_w2, enc_b2, (bf16*)encW);
  seq_kernel<<<BATCH / 16, 512, 0, stream>>>(encW, Wbu, Wtd, Wfx, b_iou, b_f,
                                             b_ih, b_hh, buh, encW);
  dec_kernel<<<(int)(NROWS / 8), 256, 0, stream>>>((const bf16*)buh, (const bf16*)encW,
                                                   cv, dec_w1, dec_b1, dec_w2, dec_b2,
                                                   (float*)d_out);
}

// Round 6
// 3241.887 us; speedup vs baseline: 2.1622x; 1.2924x over previous
//
#include <hip/hip_runtime.h>
#include <hip/hip_bf16.h>

// BDLOTreeLSTM on MI355X — round 6: 16-wave seq blocks (1024 thr, 4 waves/SIMD).
// Same fused schedule as round 5; each wave owns a narrower N-slice (nt=g*16+w)
// so per-CU panel bytes are unchanged but load concurrency doubles and per-wave
// registers shrink (acc 64->32). No B-ring (round-4 spill lesson).

constexpr int Hd    = 256;
constexpr int NBv   = 3;
constexpr int NVv   = 64;
constexpr int BATCH = 512;
constexpr long long NROWS = (long long)BATCH * NBv * NVv;   // 98304
constexpr int CLEN = 40;
constexpr int CI0 = 16, CI1 = 48;

typedef __hip_bfloat16 bf16;
typedef unsigned short ushort;
typedef __attribute__((ext_vector_type(8))) short short8;
typedef __attribute__((ext_vector_type(4))) float f32x4;

__device__ __forceinline__ float sigf(float x)   { return 1.f / (1.f + __expf(-x)); }
__device__ __forceinline__ float tanh_f(float x) { return 1.f - 2.f / (__expf(2.f * x) + 1.f); }

__device__ __forceinline__ ushort f2bf(float x) {
  unsigned u = __float_as_uint(x);
  return (ushort)((u + 0x7FFFu + ((u >> 16) & 1u)) >> 16);   // RNE
}

// ================= weight packing (round-3, verified) =========================
__global__ __launch_bounds__(256) void pack_bu_kernel(
    const float* __restrict__ W_iou, const float* __restrict__ W_f,
    const float* __restrict__ U_iou, const float* __restrict__ U_f,
    ushort* __restrict__ out)   // [512 K][1024 N]: [[W_iou|W_f];[U_iou|U_f]]
{
  int idx = blockIdx.x * 256 + threadIdx.x;
  int j = idx & 7, l = (idx >> 3) & 63, T = idx >> 9;
  int ks = T & 15, nt = T >> 4;
  int k = ks * 32 + (l >> 4) * 8 + j;
  int n = nt * 16 + (l & 15);
  float v;
  if (k < 256) v = (n < 768) ? W_iou[k * 768 + n] : W_f[k * 256 + (n - 768)];
  else         v = (n < 768) ? U_iou[(k - 256) * 768 + n] : U_f[(k - 256) * 256 + (n - 768)];
  out[idx] = f2bf(v);
}

__global__ __launch_bounds__(256) void pack_td_kernel(
    const float* __restrict__ W_ih, const float* __restrict__ W_hh,
    ushort* __restrict__ out)   // [512][1024]: [[W_ih];[W_hh]]
{
  int idx = blockIdx.x * 256 + threadIdx.x;
  int j = idx & 7, l = (idx >> 3) & 63, T = idx >> 9;
  int ks = T & 15, nt = T >> 4;
  int k = ks * 32 + (l >> 4) * 8 + j;
  int n = nt * 16 + (l & 15);
  float v = (k < 256) ? W_ih[k * 1024 + n] : W_hh[(k - 256) * 1024 + n];
  out[idx] = f2bf(v);
}

__global__ __launch_bounds__(256) void pack_wfx_kernel(
    const float* __restrict__ W_f, ushort* __restrict__ out)   // [256][256]
{
  int idx = blockIdx.x * 256 + threadIdx.x;
  int j = idx & 7, l = (idx >> 3) & 63, T = idx >> 9;
  int ks = T & 7, nt = T >> 3;
  int k = ks * 32 + (l >> 4) * 8 + j;
  int n = nt * 16 + (l & 15);
  out[idx] = f2bf(W_f[k * 256 + n]);
}

// ================= fused encoder (round-2, known-good) ========================
__global__ __launch_bounds__(256) void enc_kernel(
    const float* __restrict__ cv, const float* __restrict__ pv,
    const float* __restrict__ hints,
    const float* __restrict__ w1, const float* __restrict__ b1,
    const float* __restrict__ w2, const float* __restrict__ b2,
    bf16* __restrict__ enc)
{
  __shared__ float fs[8][9];
  __shared__ float h1s[8][Hd];
  long long row0 = (long long)blockIdx.x * 8;
  int tid = threadIdx.x;
  if (tid < 72) {
    int r = tid / 9, i = tid % 9;
    long long row = row0 + r;
    float v;
    if (i < 3)      v = cv[row * 3 + i];
    else if (i < 6) v = cv[row * 3 + (i - 3)] - pv[row * 3 + (i - 3)];
    else            v = hints[row * 3 + (i - 6)];
    fs[r][i] = v;
  }
  __syncthreads();
  int j = tid;
  {
    float w[9];
#pragma unroll
    for (int i = 0; i < 9; i++) w[i] = w1[i * Hd + j];
    float bb = b1[j];
#pragma unroll
    for (int r = 0; r < 8; r++) {
      float a = bb;
#pragma unroll
      for (int i = 0; i < 9; i++) a += fs[r][i] * w[i];
      h1s[r][j] = fmaxf(a, 0.f);
    }
  }
  __syncthreads();
  float acc[8];
  float bb2 = b2[j];
#pragma unroll
  for (int r = 0; r < 8; r++) acc[r] = bb2;
  for (int t = 0; t < Hd; t++) {
    float w = w2[t * Hd + j];
#pragma unroll
    for (int r = 0; r < 8; r++) acc[r] += h1s[r][t] * w;
  }
#pragma unroll
  for (int r = 0; r < 8; r++) enc[(row0 + r) * Hd + j] = __float2bfloat16(acc[r]);
}

// ================= seq kernel helpers =========================================
__device__ __forceinline__ short8 ldA(const ushort* buf, int row, int kbyte) {
  int off = (row * 512 + kbyte) ^ ((row & 7) << 4);
  return *(const short8*)((const char*)buf + off);
}

// Main GEMM: A [MT*16 x 512] = [Ax | Ah], B = W (frag-packed).
// 16 waves: wave w owns N-tiles {g*16+w : g in 0..3} -> jj = w*16+col.
template<int MT>
__device__ __forceinline__ void gemm_main(
    const ushort* __restrict__ W, const ushort* __restrict__ Axb_,
    const ushort* __restrict__ Ahb_, f32x4 (&acc)[MT][4],
    int w, int lane)
{
  const int col = lane & 15;
  const int kb  = (lane >> 4) * 16;
#pragma unroll 4
  for (int ks = 0; ks < 16; ++ks) {
    const ushort* Ab = (ks < 8) ? Axb_ : Ahb_;
    const int kk = ks & 7;
    short8 A[MT];
#pragma unroll
    for (int m = 0; m < MT; ++m)
      A[m] = ldA(Ab, m * 16 + col, kk * 64 + kb);
#pragma unroll
    for (int g = 0; g < 4; ++g) {
      short8 b = *(const short8*)(W + (((long long)((g * 16 + w) * 16 + ks)) * 64 + lane) * 8);
#pragma unroll
      for (int m = 0; m < MT; ++m)
        acc[m][g] = __builtin_amdgcn_mfma_f32_16x16x32_bf16(A[m], b, acc[m][g], 0, 0, 0);
    }
  }
}

// Side GEMM at coupling steps: accs += root @ [U_iou|U_f], accw += x @ W_f.
__device__ __forceinline__ void gemm_side(
    const ushort* __restrict__ Wbu, const ushort* __restrict__ Wfx,
    const ushort* __restrict__ Rhb, const ushort* __restrict__ Axc,
    f32x4 (&accs)[4], f32x4& accw, int w, int lane)
{
  const int col = lane & 15;
  const int kb  = (lane >> 4) * 16;
#pragma unroll
  for (int ks = 0; ks < 8; ++ks) {
    short8 ar = ldA(Rhb, col, ks * 64 + kb);
#pragma unroll
    for (int g = 0; g < 4; ++g) {
      short8 b = *(const short8*)(Wbu + (((g * 16 + w) * 16 + 8 + ks) * 64 + lane) * 8);
      accs[g] = __builtin_amdgcn_mfma_f32_16x16x32_bf16(ar, b, accs[g], 0, 0, 0);
    }
    short8 ax = ldA(Axc, col, ks * 64 + kb);
    short8 bw = *(const short8*)(Wfx + (((w * 8 + ks)) * 64 + lane) * 8);
    accw = __builtin_amdgcn_mfma_f32_16x16x32_bf16(ax, bw, accw, 0, 0, 0);
  }
}

#define ZACC(MT_, A_) { \
  _Pragma("unroll") for (int m_ = 0; m_ < MT_; ++m_) \
  _Pragma("unroll") for (int g_ = 0; g_ < 4; ++g_) A_[m_][g_] = zf4; }

__global__ __launch_bounds__(1024, 4) void seq_kernel(
    const ushort* enc,                      // aliases td_h -> no __restrict__
    const ushort* __restrict__ Wbu, const ushort* __restrict__ Wtd,
    const ushort* __restrict__ Wfx,
    const float* __restrict__ b_iou, const float* __restrict__ b_f,
    const float* __restrict__ b_ih,  const float* __restrict__ b_hh,
    ushort* __restrict__ bu_h, ushort* td_h)
{
  __shared__ ushort Axb[2][32 * 256];       // x-tiles, double-buffered
  __shared__ ushort Ahb[2][32 * 256];       // h-tiles, double-buffered
  __shared__ ushort Rh[2][16 * 256];        // chain roots / td seeds

  const int tid  = threadIdx.x;
  const int lane = tid & 63;
  const int w    = tid >> 6;        // wave 0..15
  const int b0   = blockIdx.x * 16;
  const int col  = lane & 15;
  const int krow = lane >> 4;
  const f32x4 zf4 = {0.f, 0.f, 0.f, 0.f};
  const short8 zero8 = {0, 0, 0, 0, 0, 0, 0, 0};

  // epilogue ownership: rows r = krow*4+q, hidden index jj = w*16+col
  const int jj = w * 16 + col;
  const float bi0 = b_iou[jj], bi1 = b_iou[256 + jj], bi2 = b_iou[512 + jj];
  const float bfv = b_f[jj];
  const float bt0 = b_ih[jj]       + b_hh[jj];
  const float bt1 = b_ih[256 + jj] + b_hh[256 + jj];
  const float bt2 = b_ih[512 + jj] + b_hh[512 + jj];
  const float bt3 = b_ih[768 + jj] + b_hh[768 + jj];

  float c2[2][4];                   // cell state per (Mtile, q)
  float rc0[4], rc1[4];             // bu-chain roots' c
  float sc0[4], sc1[4];             // td seeds' c

#define STAGE32(V, DST) { \
    int rr_ = tid >> 5, ch_ = tid & 31; \
    int mt_ = rr_ >> 4, br_ = rr_ & 15; \
    long long rowg_ = ((long long)(b0 + br_) * NBv + (mt_ + 1)) * NVv + (V); \
    short8 xv_ = *(const short8*)(enc + rowg_ * 256 + ch_ * 8); \
    *(short8*)((char*)(DST) + ((rr_ * 512 + ch_ * 16) ^ ((rr_ & 7) << 4))) = xv_; }

#define STAGE16(V, DST) if (tid < 512) { \
    int rr_ = tid >> 5, ch_ = tid & 31; \
    long long rowg_ = ((long long)(b0 + rr_) * NBv) * NVv + (V); \
    short8 xv_ = *(const short8*)(enc + rowg_ * 256 + ch_ * 8); \
    *(short8*)((char*)(DST) + ((rr_ * 512 + ch_ * 16) ^ ((rr_ & 7) << 4))) = xv_; }

#define STA(BUF, R, JJ, BITS) { \
    int off_ = ((R) * 512 + (JJ) * 2) ^ (((R) & 7) << 4); \
    (BUF)[off_ >> 1] = (BITS); }

  // ================= PHASE 1: fused bottom-up chains (v 39..0) ===============
  {
    *(short8*)((char*)Ahb[0] + tid * 16) = zero8;     // 32 rows = 16 KB
    STAGE32(CLEN - 1, Axb[0]);
#pragma unroll
    for (int m = 0; m < 2; ++m)
#pragma unroll
      for (int q = 0; q < 4; ++q) c2[m][q] = 0.f;
    __syncthreads();
    for (int s = 0; s < CLEN; ++s) {
      const int v = CLEN - 1 - s, pp = s & 1;
      if (s < CLEN - 1) STAGE32(v - 1, Axb[pp ^ 1]);
      f32x4 acc[2][4]; ZACC(2, acc);
      gemm_main<2>(Wbu, Axb[pp], Ahb[pp], acc, w, lane);
#pragma unroll
      for (int m = 0; m < 2; ++m)
#pragma unroll
        for (int q = 0; q < 4; ++q) {
          const int br = krow * 4 + q;
          float I = acc[m][0][q] + bi0;
          float O = acc[m][1][q] + bi1;
          float U = acc[m][2][q] + bi2;
          float F = acc[m][3][q] + bfv;
          float cn = sigf(I) * tanh_f(U) + sigf(F) * c2[m][q];
          float hn = sigf(O) * tanh_f(cn);
          c2[m][q] = cn;
          ushort hb = f2bf(hn);
          STA(Ahb[pp ^ 1], m * 16 + br, jj, hb);
          long long rowg = ((long long)(b0 + br) * NBv + (m + 1)) * NVv + v;
          bu_h[rowg * 256 + jj] = hb;
          if (v == 0) {
            STA(Rh[m], br, jj, hb);
            if (m == 0) rc0[q] = cn; else rc1[q] = cn;
          }
        }
      __syncthreads();
    }
  }

  // ================= PHASE 2: bottom-up parent chain (v 63..0) ===============
  {
    if (tid < 512) *(short8*)((char*)Ahb[0] + tid * 16) = zero8;   // rows 0..15
    STAGE16(NVv - 1, Axb[0]);
#pragma unroll
    for (int q = 0; q < 4; ++q) c2[0][q] = 0.f;
    __syncthreads();
    for (int s = 0; s < NVv; ++s) {
      const int v = NVv - 1 - s, pp = s & 1;
      if (s < NVv - 1) STAGE16(v - 1, Axb[pp ^ 1]);
      f32x4 acc[1][4]; ZACC(1, acc);
      gemm_main<1>(Wbu, Axb[pp], Ahb[pp], acc, w, lane);
      const int ck = (v == CI0) ? 0 : ((v == CI1) ? 1 : -1);
      f32x4 accs[4]; f32x4 accw;
      if (ck >= 0) {
#pragma unroll
        for (int g = 0; g < 4; ++g) accs[g] = zf4;
        accw = zf4;
        const ushort* Rp = (ck == 0) ? Rh[0] : Rh[1];
        gemm_side(Wbu, Wfx, Rp, Axb[pp], accs, accw, w, lane);
      }
#pragma unroll
      for (int q = 0; q < 4; ++q) {
        const int br = krow * 4 + q;
        float I  = acc[0][0][q] + bi0;
        float O  = acc[0][1][q] + bi1;
        float U  = acc[0][2][q] + bi2;
        float F1 = acc[0][3][q] + bfv;
        float fc = sigf(F1) * c2[0][q];
        if (ck >= 0) {
          I += accs[0][q]; O += accs[1][q]; U += accs[2][q];
          float wfx = accw[q] + bfv;
          float rcv = (ck == 0) ? rc0[q] : rc1[q];
          fc += sigf(wfx + accs[3][q]) * rcv;
        }
        float cn = sigf(I) * tanh_f(U) + fc;
        float hn = sigf(O) * tanh_f(cn);
        c2[0][q] = cn;
        ushort hb = f2bf(hn);
        STA(Ahb[pp ^ 1], br, jj, hb);
        long long rowg = ((long long)(b0 + br) * NBv) * NVv + v;
        bu_h[rowg * 256 + jj] = hb;
        if (v == 0) td_h[rowg * 256 + jj] = hb;      // td seed
      }
      __syncthreads();
    }
  }
  // NB: phase 2 has 64 steps -> last epilogue wrote Ahb[0]; c2[0] carries.

  // ================= PHASE 3: top-down parent chain (v 1..63) ================
  {
    STAGE16(1, Axb[0]);
    __syncthreads();
    for (int s = 0; s < NVv - 1; ++s) {
      const int v = 1 + s, pp = s & 1;
      if (s < NVv - 2) STAGE16(v + 1, Axb[pp ^ 1]);
      f32x4 acc[1][4]; ZACC(1, acc);
      gemm_main<1>(Wtd, Axb[pp], Ahb[pp], acc, w, lane);
#pragma unroll
      for (int q = 0; q < 4; ++q) {
        const int br = krow * 4 + q;
        float I = acc[0][0][q] + bt0;
        float F = acc[0][1][q] + bt1;
        float G = acc[0][2][q] + bt2;
        float O = acc[0][3][q] + bt3;
        float cn = sigf(F) * c2[0][q] + sigf(I) * tanh_f(G);
        float hn = sigf(O) * tanh_f(cn);
        c2[0][q] = cn;
        ushort hb = f2bf(hn);
        STA(Ahb[pp ^ 1], br, jj, hb);
        long long rowg = ((long long)(b0 + br) * NBv) * NVv + v;
        td_h[rowg * 256 + jj] = hb;
        if (v == CI0) { STA(Rh[0], br, jj, hb); sc0[q] = cn; }
        if (v == CI1) { STA(Rh[1], br, jj, hb); sc1[q] = cn; }
      }
      __syncthreads();
    }
  }

  // ================= PHASE 4: fused top-down chains (v 0..39) ================
  {
    {
      int rr_ = tid >> 5, ch_ = tid & 31;
      int mt_ = rr_ >> 4, br_ = rr_ & 15;
      short8 vv = *(const short8*)((const char*)Rh[mt_] +
                    ((br_ * 512 + ch_ * 16) ^ ((br_ & 7) << 4)));
      *(short8*)((char*)Ahb[0] + ((rr_ * 512 + ch_ * 16) ^ ((rr_ & 7) << 4))) = vv;
    }
    STAGE32(0, Axb[0]);
#pragma unroll
    for (int m = 0; m < 2; ++m)
#pragma unroll
      for (int q = 0; q < 4; ++q)
        c2[m][q] = (m == 0) ? sc0[q] : sc1[q];
    __syncthreads();
    for (int s = 0; s < CLEN; ++s) {
      const int v = s, pp = s & 1;
      if (s < CLEN - 1) STAGE32(v + 1, Axb[pp ^ 1]);
      f32x4 acc[2][4]; ZACC(2, acc);
      gemm_main<2>(Wtd, Axb[pp], Ahb[pp], acc, w, lane);
#pragma unroll
      for (int m = 0; m < 2; ++m)
#pragma unroll
        for (int q = 0; q < 4; ++q) {
          const int br = krow * 4 + q;
          float I = acc[m][0][q] + bt0;
          float F = acc[m][1][q] + bt1;
          float G = acc[m][2][q] + bt2;
          float O = acc[m][3][q] + bt3;
          float cn = sigf(F) * c2[m][q] + sigf(I) * tanh_f(G);
          float hn = sigf(O) * tanh_f(cn);
          c2[m][q] = cn;
          ushort hb = f2bf(hn);
          STA(Ahb[pp ^ 1], m * 16 + br, jj, hb);
          long long rowg = ((long long)(b0 + br) * NBv + (m + 1)) * NVv + v;
          td_h[rowg * 256 + jj] = hb;
        }
      __syncthreads();
    }
  }
}

// ================= decoder (round-2, known-good) ==============================
__global__ __launch_bounds__(256) void dec_kernel(
    const bf16* __restrict__ bu_h, const bf16* __restrict__ td_h,
    const float* __restrict__ cv,
    const float* __restrict__ w1, const float* __restrict__ b1,
    const float* __restrict__ w2, const float* __restrict__ b2,
    float* __restrict__ out)
{
  __shared__ float comb[8][2 * Hd];
  __shared__ float hid[8][Hd];
  __shared__ float red[4][3];
  long long row0 = (long long)blockIdx.x * 8;
  int j = threadIdx.x;
#pragma unroll
  for (int r = 0; r < 8; r++) {
    comb[r][j]      = __bfloat162float(bu_h[(row0 + r) * Hd + j]);
    comb[r][Hd + j] = __bfloat162float(td_h[(row0 + r) * Hd + j]);
  }
  __syncthreads();
  float acc[8];
  float bb = b1[j];
#pragma unroll
  for (int r = 0; r < 8; r++) acc[r] = bb;
  for (int t = 0; t < 2 * Hd; t++) {
    float w = w1[t * Hd + j];
#pragma unroll
    for (int r = 0; r < 8; r++) acc[r] += comb[r][t] * w;
  }
#pragma unroll
  for (int r = 0; r < 8; r++) hid[r][j] = fmaxf(acc[r], 0.f);
  __syncthreads();

  float w20 = w2[j * 3 + 0], w21 = w2[j * 3 + 1], w22 = w2[j * 3 + 2];
  int wid = j >> 6, lane = j & 63;
  for (int r = 0; r < 8; r++) {
    float h = hid[r][j];
    float p0 = h * w20, p1 = h * w21, p2 = h * w22;
#pragma unroll
    for (int off = 32; off > 0; off >>= 1) {
      p0 += __shfl_down(p0, off);
      p1 += __shfl_down(p1, off);
      p2 += __shfl_down(p2, off);
    }
    if (lane == 0) { red[wid][0] = p0; red[wid][1] = p1; red[wid][2] = p2; }
    __syncthreads();
    if (j < 3) {
      long long row = row0 + r;
      int v  = (int)(row % NVv);
      int br = (int)((row / NVv) % NBv);
      float res = 0.f;
      if (br == 0 || v < CLEN) {
        float s = red[0][j] + red[1][j] + red[2][j] + red[3][j];
        res = cv[row * 3 + j] + s + b2[j];
      }
      out[row * 3 + j] = res;
    }
    __syncthreads();
  }
}

extern "C" void kernel_launch(void* const* d_in, const int* in_sizes, int n_in,
                              void* d_out, int out_size, void* d_ws, size_t ws_size,
                              hipStream_t stream) {
  const float* cv     = (const float*)d_in[0];
  const float* pv     = (const float*)d_in[1];
  const float* hints  = (const float*)d_in[2];
  const float* enc_w1 = (const float*)d_in[3];
  const float* enc_b1 = (const float*)d_in[4];
  const float* enc_w2 = (const float*)d_in[5];
  const float* enc_b2 = (const float*)d_in[6];
  const float* W_iou  = (const float*)d_in[7];
  const float* b_iou  = (const float*)d_in[8];
  const float* U_iou  = (const float*)d_in[9];
  const float* W_f    = (const float*)d_in[10];
  const float* b_f    = (const float*)d_in[11];
  const float* U_f    = (const float*)d_in[12];
  const float* W_ih   = (const float*)d_in[13];
  const float* b_ih   = (const float*)d_in[14];
  const float* W_hh   = (const float*)d_in[15];
  const float* b_hh   = (const float*)d_in[16];
  const float* dec_w1 = (const float*)d_in[17];
  const float* dec_b1 = (const float*)d_in[18];
  const float* dec_w2 = (const float*)d_in[19];
  const float* dec_b2 = (const float*)d_in[20];

  size_t act = (size_t)NROWS * 256;
  size_t need = (2 * act + 2 * (size_t)(512 * 1024) + 256 * 256) * sizeof(ushort);
  if (ws_size < need) return;

  ushort* encW = (ushort*)d_ws;         // enc, overwritten in place as td_h
  ushort* buh  = encW + act;
  ushort* Wbu  = buh + act;
  ushort* Wtd  = Wbu + 512 * 1024;
  ushort* Wfx  = Wtd + 512 * 1024;

  pack_bu_kernel<<<2048, 256, 0, stream>>>(W_iou, W_f, U_iou, U_f, Wbu);
  pack_td_kernel<<<2048, 256, 0, stream>>>(W_ih, W_hh, Wtd);
  pack_wfx_kernel<<<256, 256, 0, stream>>>(W_f, Wfx);

  enc_kernel<<<(int)(NROWS / 8), 256, 0, stream>>>(cv, pv, hints, enc_w1, enc_b1,
                                                   enc_w2, enc_b2, (bf16*)encW);
  seq_kernel<<<BATCH / 16, 1024, 0, stream>>>(encW, Wbu, Wtd, Wfx, b_iou, b_f,
                                              b_ih, b_hh, buh, encW);
  dec_kernel<<<(int)(NROWS / 8), 256, 0, stream>>>((const bf16*)buh, (const bf16*)encW,
                                                   cv, dec_w1, dec_b1, dec_w2, dec_b2,
                                                   (float*)d_out);
}

// Round 7
// 2496.632 us; speedup vs baseline: 2.8077x; 1.2985x over previous
//
#include <hip/hip_runtime.h>
#include <hip/hip_bf16.h>

// BDLOTreeLSTM on MI355X — round 7: seq unchanged (round-6, verified).
// enc/dec rebuilt on MFMA with packed-B panels + swizzled LDS A-tiles.

constexpr int Hd    = 256;
constexpr int NBv   = 3;
constexpr int NVv   = 64;
constexpr int BATCH = 512;
constexpr long long NROWS = (long long)BATCH * NBv * NVv;   // 98304
constexpr int CLEN = 40;
constexpr int CI0 = 16, CI1 = 48;

typedef __hip_bfloat16 bf16;
typedef unsigned short ushort;
typedef __attribute__((ext_vector_type(8))) short short8;
typedef __attribute__((ext_vector_type(4))) float f32x4;

__device__ __forceinline__ float sigf(float x)   { return 1.f / (1.f + __expf(-x)); }
__device__ __forceinline__ float tanh_f(float x) { return 1.f - 2.f / (__expf(2.f * x) + 1.f); }

__device__ __forceinline__ ushort f2bf(float x) {
  unsigned u = __float_as_uint(x);
  return (ushort)((u + 0x7FFFu + ((u >> 16) & 1u)) >> 16);   // RNE
}

// ================= weight packing =============================================
// B-frag: lane l holds B[k][n], k = ks*32+(l>>4)*8+j, n = nt*16+(l&15);
// packed at out[((nt*NKS + ks)*64 + l)*8 + j].

__global__ __launch_bounds__(256) void pack_bu_kernel(
    const float* __restrict__ W_iou, const float* __restrict__ W_f,
    const float* __restrict__ U_iou, const float* __restrict__ U_f,
    ushort* __restrict__ out)   // [512 K][1024 N]: [[W_iou|W_f];[U_iou|U_f]]
{
  int idx = blockIdx.x * 256 + threadIdx.x;
  int j = idx & 7, l = (idx >> 3) & 63, T = idx >> 9;
  int ks = T & 15, nt = T >> 4;
  int k = ks * 32 + (l >> 4) * 8 + j;
  int n = nt * 16 + (l & 15);
  float v;
  if (k < 256) v = (n < 768) ? W_iou[k * 768 + n] : W_f[k * 256 + (n - 768)];
  else         v = (n < 768) ? U_iou[(k - 256) * 768 + n] : U_f[(k - 256) * 256 + (n - 768)];
  out[idx] = f2bf(v);
}

__global__ __launch_bounds__(256) void pack_td_kernel(
    const float* __restrict__ W_ih, const float* __restrict__ W_hh,
    ushort* __restrict__ out)   // [512][1024]: [[W_ih];[W_hh]]
{
  int idx = blockIdx.x * 256 + threadIdx.x;
  int j = idx & 7, l = (idx >> 3) & 63, T = idx >> 9;
  int ks = T & 15, nt = T >> 4;
  int k = ks * 32 + (l >> 4) * 8 + j;
  int n = nt * 16 + (l & 15);
  float v = (k < 256) ? W_ih[k * 1024 + n] : W_hh[(k - 256) * 1024 + n];
  out[idx] = f2bf(v);
}

__global__ __launch_bounds__(256) void pack_wfx_kernel(
    const float* __restrict__ W_f, ushort* __restrict__ out)   // [256][256], NKS=8
{
  int idx = blockIdx.x * 256 + threadIdx.x;
  int j = idx & 7, l = (idx >> 3) & 63, T = idx >> 9;
  int ks = T & 7, nt = T >> 3;
  int k = ks * 32 + (l >> 4) * 8 + j;
  int n = nt * 16 + (l & 15);
  out[idx] = f2bf(W_f[k * 256 + n]);
}

__global__ __launch_bounds__(256) void pack_encw2_kernel(
    const float* __restrict__ w2, ushort* __restrict__ out)   // [256][256], NKS=8
{
  int idx = blockIdx.x * 256 + threadIdx.x;          // 65536
  int j = idx & 7, l = (idx >> 3) & 63, T = idx >> 9;
  int ks = T & 7, nt = T >> 3;
  int k = ks * 32 + (l >> 4) * 8 + j;
  int n = nt * 16 + (l & 15);
  out[idx] = f2bf(w2[k * 256 + n]);
}

__global__ __launch_bounds__(256) void pack_decw1_kernel(
    const float* __restrict__ w1, ushort* __restrict__ out)   // [512][256], NKS=16
{
  int idx = blockIdx.x * 256 + threadIdx.x;          // 131072
  int j = idx & 7, l = (idx >> 3) & 63, T = idx >> 9;
  int ks = T & 15, nt = T >> 4;
  int k = ks * 32 + (l >> 4) * 8 + j;
  int n = nt * 16 + (l & 15);
  out[idx] = f2bf(w1[k * 256 + n]);
}

__global__ __launch_bounds__(256) void pack_decw2_kernel(
    const float* __restrict__ w2, ushort* __restrict__ out)   // [256][3->16], NKS=8
{
  int idx = blockIdx.x * 256 + threadIdx.x;          // 4096
  int j = idx & 7, l = (idx >> 3) & 63, T = idx >> 9;
  int ks = T & 7;                                    // nt = 0
  int k = ks * 32 + (l >> 4) * 8 + j;
  int n = l & 15;
  out[idx] = (n < 3) ? f2bf(w2[k * 3 + n]) : (ushort)0;
}

// ================= LDS A-tile helpers =========================================
__device__ __forceinline__ short8 ldA(const ushort* buf, int row, int kbyte) {
  int off = (row * 512 + kbyte) ^ ((row & 7) << 4);
  return *(const short8*)((const char*)buf + off);
}
__device__ __forceinline__ short8 ldA1024(const ushort* buf, int row, int kbyte) {
  int off = (row * 1024 + kbyte) ^ ((row & 7) << 4);
  return *(const short8*)((const char*)buf + off);
}
#define STA(BUF, R, JJ, BITS) { \
    int off_ = ((R) * 512 + (JJ) * 2) ^ (((R) & 7) << 4); \
    (BUF)[off_ >> 1] = (BITS); }

// ================= encoder: L1 VALU (K=9) + L2 MFMA ===========================
__global__ __launch_bounds__(256) void enc_kernel(
    const float* __restrict__ cv, const float* __restrict__ pv,
    const float* __restrict__ hints,
    const float* __restrict__ w1, const float* __restrict__ b1,
    const ushort* __restrict__ w2p, const float* __restrict__ b2,
    ushort* __restrict__ enc)
{
  __shared__ float fs[32][10];
  __shared__ ushort h1L[32 * 256];
  const long long row0 = (long long)blockIdx.x * 32;
  const int tid = threadIdx.x;
  if (tid < 96) {
    int r = tid / 3, c = tid % 3;
    long long row = row0 + r;
    float a = cv[row * 3 + c];
    fs[r][c]     = a;
    fs[r][3 + c] = a - pv[row * 3 + c];
    fs[r][6 + c] = hints[row * 3 + c];
  }
  __syncthreads();
  {
    const int j = tid;
    float wc[9];
#pragma unroll
    for (int i = 0; i < 9; ++i) wc[i] = w1[i * 256 + j];
    const float bb = b1[j];
    for (int r = 0; r < 32; ++r) {
      float a = bb;
#pragma unroll
      for (int i = 0; i < 9; ++i) a += fs[r][i] * wc[i];
      ushort hb = f2bf(fmaxf(a, 0.f));
      STA(h1L, r, j, hb);
    }
  }
  __syncthreads();
  const int lane = tid & 63, w = tid >> 6;
  const int col = lane & 15, krow = lane >> 4, kb = krow * 16;
  const f32x4 zf4 = {0.f, 0.f, 0.f, 0.f};
  f32x4 acc[2][4];
#pragma unroll
  for (int m = 0; m < 2; ++m)
#pragma unroll
    for (int g = 0; g < 4; ++g) acc[m][g] = zf4;
#pragma unroll
  for (int ks = 0; ks < 8; ++ks) {
    short8 A[2];
#pragma unroll
    for (int m = 0; m < 2; ++m) A[m] = ldA(h1L, m * 16 + col, ks * 64 + kb);
#pragma unroll
    for (int g = 0; g < 4; ++g) {
      short8 b = *(const short8*)(w2p + ((((w * 4 + g) * 8 + ks) * 64 + lane)) * 8);
#pragma unroll
      for (int m = 0; m < 2; ++m)
        acc[m][g] = __builtin_amdgcn_mfma_f32_16x16x32_bf16(A[m], b, acc[m][g], 0, 0, 0);
    }
  }
#pragma unroll
  for (int g = 0; g < 4; ++g) {
    const int jj = (w * 4 + g) * 16 + col;
    const float bb = b2[jj];
#pragma unroll
    for (int m = 0; m < 2; ++m)
#pragma unroll
      for (int q = 0; q < 4; ++q) {
        long long row = row0 + m * 16 + krow * 4 + q;
        enc[row * 256 + jj] = f2bf(acc[m][g][q] + bb);
      }
  }
}

// ================= seq kernel (round-6, verified — UNCHANGED) =================
template<int MT>
__device__ __forceinline__ void gemm_main(
    const ushort* __restrict__ W, const ushort* __restrict__ Axb_,
    const ushort* __restrict__ Ahb_, f32x4 (&acc)[MT][4],
    int w, int lane)
{
  const int col = lane & 15;
  const int kb  = (lane >> 4) * 16;
#pragma unroll 4
  for (int ks = 0; ks < 16; ++ks) {
    const ushort* Ab = (ks < 8) ? Axb_ : Ahb_;
    const int kk = ks & 7;
    short8 A[MT];
#pragma unroll
    for (int m = 0; m < MT; ++m)
      A[m] = ldA(Ab, m * 16 + col, kk * 64 + kb);
#pragma unroll
    for (int g = 0; g < 4; ++g) {
      short8 b = *(const short8*)(W + (((long long)((g * 16 + w) * 16 + ks)) * 64 + lane) * 8);
#pragma unroll
      for (int m = 0; m < MT; ++m)
        acc[m][g] = __builtin_amdgcn_mfma_f32_16x16x32_bf16(A[m], b, acc[m][g], 0, 0, 0);
    }
  }
}

__device__ __forceinline__ void gemm_side(
    const ushort* __restrict__ Wbu, const ushort* __restrict__ Wfx,
    const ushort* __restrict__ Rhb, const ushort* __restrict__ Axc,
    f32x4 (&accs)[4], f32x4& accw, int w, int lane)
{
  const int col = lane & 15;
  const int kb  = (lane >> 4) * 16;
#pragma unroll
  for (int ks = 0; ks < 8; ++ks) {
    short8 ar = ldA(Rhb, col, ks * 64 + kb);
#pragma unroll
    for (int g = 0; g < 4; ++g) {
      short8 b = *(const short8*)(Wbu + (((g * 16 + w) * 16 + 8 + ks) * 64 + lane) * 8);
      accs[g] = __builtin_amdgcn_mfma_f32_16x16x32_bf16(ar, b, accs[g], 0, 0, 0);
    }
    short8 ax = ldA(Axc, col, ks * 64 + kb);
    short8 bw = *(const short8*)(Wfx + (((w * 8 + ks)) * 64 + lane) * 8);
    accw = __builtin_amdgcn_mfma_f32_16x16x32_bf16(ax, bw, accw, 0, 0, 0);
  }
}

#define ZACC(MT_, A_) { \
  _Pragma("unroll") for (int m_ = 0; m_ < MT_; ++m_) \
  _Pragma("unroll") for (int g_ = 0; g_ < 4; ++g_) A_[m_][g_] = zf4; }

__global__ __launch_bounds__(1024, 4) void seq_kernel(
    const ushort* enc,                      // aliases td_h -> no __restrict__
    const ushort* __restrict__ Wbu, const ushort* __restrict__ Wtd,
    const ushort* __restrict__ Wfx,
    const float* __restrict__ b_iou, const float* __restrict__ b_f,
    const float* __restrict__ b_ih,  const float* __restrict__ b_hh,
    ushort* __restrict__ bu_h, ushort* td_h)
{
  __shared__ ushort Axb[2][32 * 256];
  __shared__ ushort Ahb[2][32 * 256];
  __shared__ ushort Rh[2][16 * 256];

  const int tid  = threadIdx.x;
  const int lane = tid & 63;
  const int w    = tid >> 6;
  const int b0   = blockIdx.x * 16;
  const int col  = lane & 15;
  const int krow = lane >> 4;
  const f32x4 zf4 = {0.f, 0.f, 0.f, 0.f};
  const short8 zero8 = {0, 0, 0, 0, 0, 0, 0, 0};

  const int jj = w * 16 + col;
  const float bi0 = b_iou[jj], bi1 = b_iou[256 + jj], bi2 = b_iou[512 + jj];
  const float bfv = b_f[jj];
  const float bt0 = b_ih[jj]       + b_hh[jj];
  const float bt1 = b_ih[256 + jj] + b_hh[256 + jj];
  const float bt2 = b_ih[512 + jj] + b_hh[512 + jj];
  const float bt3 = b_ih[768 + jj] + b_hh[768 + jj];

  float c2[2][4];
  float rc0[4], rc1[4];
  float sc0[4], sc1[4];

#define STAGE32(V, DST) { \
    int rr_ = tid >> 5, ch_ = tid & 31; \
    int mt_ = rr_ >> 4, br_ = rr_ & 15; \
    long long rowg_ = ((long long)(b0 + br_) * NBv + (mt_ + 1)) * NVv + (V); \
    short8 xv_ = *(const short8*)(enc + rowg_ * 256 + ch_ * 8); \
    *(short8*)((char*)(DST) + ((rr_ * 512 + ch_ * 16) ^ ((rr_ & 7) << 4))) = xv_; }

#define STAGE16(V, DST) if (tid < 512) { \
    int rr_ = tid >> 5, ch_ = tid & 31; \
    long long rowg_ = ((long long)(b0 + rr_) * NBv) * NVv + (V); \
    short8 xv_ = *(const short8*)(enc + rowg_ * 256 + ch_ * 8); \
    *(short8*)((char*)(DST) + ((rr_ * 512 + ch_ * 16) ^ ((rr_ & 7) << 4))) = xv_; }

  // ================= PHASE 1: fused bottom-up chains (v 39..0) ===============
  {
    *(short8*)((char*)Ahb[0] + tid * 16) = zero8;
    STAGE32(CLEN - 1, Axb[0]);
#pragma unroll
    for (int m = 0; m < 2; ++m)
#pragma unroll
      for (int q = 0; q < 4; ++q) c2[m][q] = 0.f;
    __syncthreads();
    for (int s = 0; s < CLEN; ++s) {
      const int v = CLEN - 1 - s, pp = s & 1;
      if (s < CLEN - 1) STAGE32(v - 1, Axb[pp ^ 1]);
      f32x4 acc[2][4]; ZACC(2, acc);
      gemm_main<2>(Wbu, Axb[pp], Ahb[pp], acc, w, lane);
#pragma unroll
      for (int m = 0; m < 2; ++m)
#pragma unroll
        for (int q = 0; q < 4; ++q) {
          const int br = krow * 4 + q;
          float I = acc[m][0][q] + bi0;
          float O = acc[m][1][q] + bi1;
          float U = acc[m][2][q] + bi2;
          float F = acc[m][3][q] + bfv;
          float cn = sigf(I) * tanh_f(U) + sigf(F) * c2[m][q];
          float hn = sigf(O) * tanh_f(cn);
          c2[m][q] = cn;
          ushort hb = f2bf(hn);
          STA(Ahb[pp ^ 1], m * 16 + br, jj, hb);
          long long rowg = ((long long)(b0 + br) * NBv + (m + 1)) * NVv + v;
          bu_h[rowg * 256 + jj] = hb;
          if (v == 0) {
            STA(Rh[m], br, jj, hb);
            if (m == 0) rc0[q] = cn; else rc1[q] = cn;
          }
        }
      __syncthreads();
    }
  }

  // ================= PHASE 2: bottom-up parent chain (v 63..0) ===============
  {
    if (tid < 512) *(short8*)((char*)Ahb[0] + tid * 16) = zero8;
    STAGE16(NVv - 1, Axb[0]);
#pragma unroll
    for (int q = 0; q < 4; ++q) c2[0][q] = 0.f;
    __syncthreads();
    for (int s = 0; s < NVv; ++s) {
      const int v = NVv - 1 - s, pp = s & 1;
      if (s < NVv - 1) STAGE16(v - 1, Axb[pp ^ 1]);
      f32x4 acc[1][4]; ZACC(1, acc);
      gemm_main<1>(Wbu, Axb[pp], Ahb[pp], acc, w, lane);
      const int ck = (v == CI0) ? 0 : ((v == CI1) ? 1 : -1);
      f32x4 accs[4]; f32x4 accw;
      if (ck >= 0) {
#pragma unroll
        for (int g = 0; g < 4; ++g) accs[g] = zf4;
        accw = zf4;
        const ushort* Rp = (ck == 0) ? Rh[0] : Rh[1];
        gemm_side(Wbu, Wfx, Rp, Axb[pp], accs, accw, w, lane);
      }
#pragma unroll
      for (int q = 0; q < 4; ++q) {
        const int br = krow * 4 + q;
        float I  = acc[0][0][q] + bi0;
        float O  = acc[0][1][q] + bi1;
        float U  = acc[0][2][q] + bi2;
        float F1 = acc[0][3][q] + bfv;
        float fc = sigf(F1) * c2[0][q];
        if (ck >= 0) {
          I += accs[0][q]; O += accs[1][q]; U += accs[2][q];
          float wfx = accw[q] + bfv;
          float rcv = (ck == 0) ? rc0[q] : rc1[q];
          fc += sigf(wfx + accs[3][q]) * rcv;
        }
        float cn = sigf(I) * tanh_f(U) + fc;
        float hn = sigf(O) * tanh_f(cn);
        c2[0][q] = cn;
        ushort hb = f2bf(hn);
        STA(Ahb[pp ^ 1], br, jj, hb);
        long long rowg = ((long long)(b0 + br) * NBv) * NVv + v;
        bu_h[rowg * 256 + jj] = hb;
        if (v == 0) td_h[rowg * 256 + jj] = hb;
      }
      __syncthreads();
    }
  }

  // ================= PHASE 3: top-down parent chain (v 1..63) ================
  {
    STAGE16(1, Axb[0]);
    __syncthreads();
    for (int s = 0; s < NVv - 1; ++s) {
      const int v = 1 + s, pp = s & 1;
      if (s < NVv - 2) STAGE16(v + 1, Axb[pp ^ 1]);
      f32x4 acc[1][4]; ZACC(1, acc);
      gemm_main<1>(Wtd, Axb[pp], Ahb[pp], acc, w, lane);
#pragma unroll
      for (int q = 0; q < 4; ++q) {
        const int br = krow * 4 + q;
        float I = acc[0][0][q] + bt0;
        float F = acc[0][1][q] + bt1;
        float G = acc[0][2][q] + bt2;
        float O = acc[0][3][q] + bt3;
        float cn = sigf(F) * c2[0][q] + sigf(I) * tanh_f(G);
        float hn = sigf(O) * tanh_f(cn);
        c2[0][q] = cn;
        ushort hb = f2bf(hn);
        STA(Ahb[pp ^ 1], br, jj, hb);
        long long rowg = ((long long)(b0 + br) * NBv) * NVv + v;
        td_h[rowg * 256 + jj] = hb;
        if (v == CI0) { STA(Rh[0], br, jj, hb); sc0[q] = cn; }
        if (v == CI1) { STA(Rh[1], br, jj, hb); sc1[q] = cn; }
      }
      __syncthreads();
    }
  }

  // ================= PHASE 4: fused top-down chains (v 0..39) ================
  {
    {
      int rr_ = tid >> 5, ch_ = tid & 31;
      int mt_ = rr_ >> 4, br_ = rr_ & 15;
      short8 vv = *(const short8*)((const char*)Rh[mt_] +
                    ((br_ * 512 + ch_ * 16) ^ ((br_ & 7) << 4)));
      *(short8*)((char*)Ahb[0] + ((rr_ * 512 + ch_ * 16) ^ ((rr_ & 7) << 4))) = vv;
    }
    STAGE32(0, Axb[0]);
#pragma unroll
    for (int m = 0; m < 2; ++m)
#pragma unroll
      for (int q = 0; q < 4; ++q)
        c2[m][q] = (m == 0) ? sc0[q] : sc1[q];
    __syncthreads();
    for (int s = 0; s < CLEN; ++s) {
      const int v = s, pp = s & 1;
      if (s < CLEN - 1) STAGE32(v + 1, Axb[pp ^ 1]);
      f32x4 acc[2][4]; ZACC(2, acc);
      gemm_main<2>(Wtd, Axb[pp], Ahb[pp], acc, w, lane);
#pragma unroll
      for (int m = 0; m < 2; ++m)
#pragma unroll
        for (int q = 0; q < 4; ++q) {
          const int br = krow * 4 + q;
          float I = acc[m][0][q] + bt0;
          float F = acc[m][1][q] + bt1;
          float G = acc[m][2][q] + bt2;
          float O = acc[m][3][q] + bt3;
          float cn = sigf(F) * c2[m][q] + sigf(I) * tanh_f(G);
          float hn = sigf(O) * tanh_f(cn);
          c2[m][q] = cn;
          ushort hb = f2bf(hn);
          STA(Ahb[pp ^ 1], m * 16 + br, jj, hb);
          long long rowg = ((long long)(b0 + br) * NBv + (m + 1)) * NVv + v;
          td_h[rowg * 256 + jj] = hb;
        }
      __syncthreads();
    }
  }
}

// ================= decoder: MFMA L1 + wave-0 MFMA L2 ==========================
__global__ __launch_bounds__(256) void dec_kernel(
    const ushort* __restrict__ bu_h, const ushort* __restrict__ td_h,
    const float* __restrict__ cv,
    const ushort* __restrict__ w1p, const float* __restrict__ b1,
    const ushort* __restrict__ w2p, const float* __restrict__ b2,
    float* __restrict__ out)
{
  __shared__ ushort combL[32 * 512];   // 32 KB, 1024B rows, swizzled
  __shared__ ushort hidL[32 * 256];    // 16 KB, 512B rows, swizzled
  const long long row0 = (long long)blockIdx.x * 32;
  const int tid = threadIdx.x;

  // stage comb = [bu_h | td_h]
#pragma unroll
  for (int h = 0; h < 8; ++h) {
    int cid = tid + h * 256;
    int rr = cid >> 6, ch = cid & 63;
    long long row = row0 + rr;
    short8 v = (ch < 32)
        ? *(const short8*)(bu_h + row * 256 + ch * 8)
        : *(const short8*)(td_h + row * 256 + (ch - 32) * 8);
    *(short8*)((char*)combL + ((rr * 1024 + ch * 16) ^ ((rr & 7) << 4))) = v;
  }
  __syncthreads();

  const int lane = tid & 63, w = tid >> 6;
  const int col = lane & 15, krow = lane >> 4, kb = krow * 16;
  const f32x4 zf4 = {0.f, 0.f, 0.f, 0.f};
  f32x4 acc[2][4];
#pragma unroll
  for (int m = 0; m < 2; ++m)
#pragma unroll
    for (int g = 0; g < 4; ++g) acc[m][g] = zf4;
#pragma unroll 4
  for (int ks = 0; ks < 16; ++ks) {
    short8 A[2];
#pragma unroll
    for (int m = 0; m < 2; ++m) A[m] = ldA1024(combL, m * 16 + col, ks * 64 + kb);
#pragma unroll
    for (int g = 0; g < 4; ++g) {
      short8 b = *(const short8*)(w1p + ((((w * 4 + g) * 16 + ks) * 64 + lane)) * 8);
#pragma unroll
      for (int m = 0; m < 2; ++m)
        acc[m][g] = __builtin_amdgcn_mfma_f32_16x16x32_bf16(A[m], b, acc[m][g], 0, 0, 0);
    }
  }
#pragma unroll
  for (int g = 0; g < 4; ++g) {
    const int jj = (w * 4 + g) * 16 + col;
    const float bb = b1[jj];
#pragma unroll
    for (int m = 0; m < 2; ++m)
#pragma unroll
      for (int q = 0; q < 4; ++q) {
        ushort hb = f2bf(fmaxf(acc[m][g][q] + bb, 0.f));
        STA(hidL, m * 16 + krow * 4 + q, jj, hb);
      }
  }
  __syncthreads();

  if (w == 0) {
    f32x4 acc2[2]; acc2[0] = zf4; acc2[1] = zf4;
#pragma unroll
    for (int ks = 0; ks < 8; ++ks) {
      short8 bv = *(const short8*)(w2p + ((ks * 64 + lane)) * 8);
#pragma unroll
      for (int m = 0; m < 2; ++m) {
        short8 A = ldA(hidL, m * 16 + col, ks * 64 + kb);
        acc2[m] = __builtin_amdgcn_mfma_f32_16x16x32_bf16(A, bv, acc2[m], 0, 0, 0);
      }
    }
    if (col < 3) {
      const float bb = b2[col];
#pragma unroll
      for (int m = 0; m < 2; ++m)
#pragma unroll
        for (int q = 0; q < 4; ++q) {
          long long row = row0 + m * 16 + krow * 4 + q;
          int v  = (int)(row & 63);
          int br = (int)((row >> 6) % 3);
          float res = 0.f;
          if (br == 0 || v < CLEN)
            res = cv[row * 3 + col] + acc2[m][q] + bb;
          out[row * 3 + col] = res;
        }
    }
  }
}

extern "C" void kernel_launch(void* const* d_in, const int* in_sizes, int n_in,
                              void* d_out, int out_size, void* d_ws, size_t ws_size,
                              hipStream_t stream) {
  const float* cv     = (const float*)d_in[0];
  const float* pv     = (const float*)d_in[1];
  const float* hints  = (const float*)d_in[2];
  const float* enc_w1 = (const float*)d_in[3];
  const float* enc_b1 = (const float*)d_in[4];
  const float* enc_w2 = (const float*)d_in[5];
  const float* enc_b2 = (const float*)d_in[6];
  const float* W_iou  = (const float*)d_in[7];
  const float* b_iou  = (const float*)d_in[8];
  const float* U_iou  = (const float*)d_in[9];
  const float* W_f    = (const float*)d_in[10];
  const float* b_f    = (const float*)d_in[11];
  const float* U_f    = (const float*)d_in[12];
  const float* W_ih   = (const float*)d_in[13];
  const float* b_ih   = (const float*)d_in[14];
  const float* W_hh   = (const float*)d_in[15];
  const float* b_hh   = (const float*)d_in[16];
  const float* dec_w1 = (const float*)d_in[17];
  const float* dec_b1 = (const float*)d_in[18];
  const float* dec_w2 = (const float*)d_in[19];
  const float* dec_b2 = (const float*)d_in[20];

  size_t act = (size_t)NROWS * 256;
  size_t wb = 512 * 1024;             // Wbu/Wtd elems
  size_t need = (2 * act + 2 * wb + 65536 /*Wfx*/ + 65536 /*encw2*/ +
                 131072 /*decw1*/ + 4096 /*decw2*/) * sizeof(ushort);
  if (ws_size < need) return;

  ushort* encW   = (ushort*)d_ws;     // enc, overwritten in place as td_h
  ushort* buh    = encW + act;
  ushort* Wbu    = buh + act;
  ushort* Wtd    = Wbu + wb;
  ushort* Wfx    = Wtd + wb;
  ushort* encw2p = Wfx + 65536;
  ushort* decw1p = encw2p + 65536;
  ushort* decw2p = decw1p + 131072;

  pack_bu_kernel<<<2048, 256, 0, stream>>>(W_iou, W_f, U_iou, U_f, Wbu);
  pack_td_kernel<<<2048, 256, 0, stream>>>(W_ih, W_hh, Wtd);
  pack_wfx_kernel<<<256, 256, 0, stream>>>(W_f, Wfx);
  pack_encw2_kernel<<<256, 256, 0, stream>>>(enc_w2, encw2p);
  pack_decw1_kernel<<<512, 256, 0, stream>>>(dec_w1, decw1p);
  pack_decw2_kernel<<<16, 256, 0, stream>>>(dec_w2, decw2p);

  enc_kernel<<<(int)(NROWS / 32), 256, 0, stream>>>(cv, pv, hints, enc_w1, enc_b1,
                                                    encw2p, enc_b2, encW);
  seq_kernel<<<BATCH / 16, 1024, 0, stream>>>(encW, Wbu, Wtd, Wfx, b_iou, b_f,
                                              b_ih, b_hh, buh, encW);
  dec_kernel<<<(int)(NROWS / 32), 256, 0, stream>>>(buh, encW, cv, decw1p, dec_b1,
                                                    decw2p, dec_b2, (float*)d_out);
}

// Round 8
// 1936.329 us; speedup vs baseline: 3.6201x; 1.2894x over previous
//
#include <hip/hip_runtime.h>
#include <hip/hip_bf16.h>
#include <hip/hip_fp8.h>

// BDLOTreeLSTM on MI355X — round 8: fp8(e4m3) recurrent GEMM (panel 1MB->512KB
// per step) + T14 split staging. enc/dec (bf16 MFMA, round-7 verified) intact.

constexpr int Hd    = 256;
constexpr int NBv   = 3;
constexpr int NVv   = 64;
constexpr int BATCH = 512;
constexpr long long NROWS = (long long)BATCH * NBv * NVv;   // 98304
constexpr int CLEN = 40;
constexpr int CI0 = 16, CI1 = 48;

typedef __hip_bfloat16 bf16;
typedef unsigned short ushort;
typedef unsigned char u8;
typedef __attribute__((ext_vector_type(8))) short short8;
typedef __attribute__((ext_vector_type(4))) float f32x4;
typedef __attribute__((ext_vector_type(2))) long longx2;

__device__ __forceinline__ float sigf(float x)   { return 1.f / (1.f + __expf(-x)); }
__device__ __forceinline__ float tanh_f(float x) { return 1.f - 2.f / (__expf(2.f * x) + 1.f); }

__device__ __forceinline__ ushort f2bf(float x) {
  unsigned u = __float_as_uint(x);
  return (ushort)((u + 0x7FFFu + ((u >> 16) & 1u)) >> 16);   // RNE
}
__device__ __forceinline__ float bf2f(ushort u) {
  return __uint_as_float(((unsigned)u) << 16);
}
__device__ __forceinline__ u8 f2fp8(float x) {
  __hip_fp8_e4m3 q(x);
  return (u8)q.__x;
}

// ================= fp8 weight packing =========================================
// B-frag (16x16x32 fp8): lane l holds B[k][n], k = ks*32+(l>>4)*8+j, n = nt*16+(l&15).
// Pair-packed: byte at ((nt*(NKS/2)+kp)*64+l)*16 + s*8 + j, ks = kp*2+s.
// One thread packs 8 bytes (one (s,l,T) unit).

__global__ __launch_bounds__(256) void pack_bu8_kernel(
    const float* __restrict__ W_iou, const float* __restrict__ W_f,
    const float* __restrict__ U_iou, const float* __restrict__ U_f,
    u8* __restrict__ out)   // [512 K][1024 N]: [[W_iou|W_f];[U_iou|U_f]]
{
  int u = blockIdx.x * 256 + threadIdx.x;      // 0..65535
  int s = u & 1, l = (u >> 1) & 63, T = u >> 7;
  int kp = T & 7, nt = T >> 3;
  int ks = kp * 2 + s;
  int k0 = ks * 32 + (l >> 4) * 8;
  int n  = nt * 16 + (l & 15);
  unsigned long long r = 0;
#pragma unroll
  for (int j = 0; j < 8; ++j) {
    int k = k0 + j;
    float v;
    if (k < 256) v = (n < 768) ? W_iou[k * 768 + n] : W_f[k * 256 + (n - 768)];
    else         v = (n < 768) ? U_iou[(k - 256) * 768 + n] : U_f[(k - 256) * 256 + (n - 768)];
    r |= ((unsigned long long)f2fp8(v)) << (8 * j);
  }
  *(unsigned long long*)(out + (size_t)u * 8) = r;
}

__global__ __launch_bounds__(256) void pack_td8_kernel(
    const float* __restrict__ W_ih, const float* __restrict__ W_hh,
    u8* __restrict__ out)   // [512][1024]: [[W_ih];[W_hh]]
{
  int u = blockIdx.x * 256 + threadIdx.x;
  int s = u & 1, l = (u >> 1) & 63, T = u >> 7;
  int kp = T & 7, nt = T >> 3;
  int ks = kp * 2 + s;
  int k0 = ks * 32 + (l >> 4) * 8;
  int n  = nt * 16 + (l & 15);
  unsigned long long r = 0;
#pragma unroll
  for (int j = 0; j < 8; ++j) {
    int k = k0 + j;
    float v = (k < 256) ? W_ih[k * 1024 + n] : W_hh[(k - 256) * 1024 + n];
    r |= ((unsigned long long)f2fp8(v)) << (8 * j);
  }
  *(unsigned long long*)(out + (size_t)u * 8) = r;
}

__global__ __launch_bounds__(256) void pack_wfx8_kernel(
    const float* __restrict__ W_f, u8* __restrict__ out)   // [256][256], NKS=8
{
  int u = blockIdx.x * 256 + threadIdx.x;      // 0..8191
  int s = u & 1, l = (u >> 1) & 63, T = u >> 7;
  int kp = T & 3, nt = T >> 2;
  int ks = kp * 2 + s;
  int k0 = ks * 32 + (l >> 4) * 8;
  int n  = nt * 16 + (l & 15);
  unsigned long long r = 0;
#pragma unroll
  for (int j = 0; j < 8; ++j)
    r |= ((unsigned long long)f2fp8(W_f[(k0 + j) * 256 + n])) << (8 * j);
  *(unsigned long long*)(out + (size_t)u * 8) = r;
}

// ================= bf16 packs for enc/dec (round-7 verified) ==================
__global__ __launch_bounds__(256) void pack_encw2_kernel(
    const float* __restrict__ w2, ushort* __restrict__ out)   // [256][256], NKS=8
{
  int idx = blockIdx.x * 256 + threadIdx.x;
  int j = idx & 7, l = (idx >> 3) & 63, T = idx >> 9;
  int ks = T & 7, nt = T >> 3;
  int k = ks * 32 + (l >> 4) * 8 + j;
  int n = nt * 16 + (l & 15);
  out[idx] = f2bf(w2[k * 256 + n]);
}

__global__ __launch_bounds__(256) void pack_decw1_kernel(
    const float* __restrict__ w1, ushort* __restrict__ out)   // [512][256], NKS=16
{
  int idx = blockIdx.x * 256 + threadIdx.x;
  int j = idx & 7, l = (idx >> 3) & 63, T = idx >> 9;
  int ks = T & 15, nt = T >> 4;
  int k = ks * 32 + (l >> 4) * 8 + j;
  int n = nt * 16 + (l & 15);
  out[idx] = f2bf(w1[k * 256 + n]);
}

__global__ __launch_bounds__(256) void pack_decw2_kernel(
    const float* __restrict__ w2, ushort* __restrict__ out)   // [256][3->16], NKS=8
{
  int idx = blockIdx.x * 256 + threadIdx.x;
  int j = idx & 7, l = (idx >> 3) & 63, T = idx >> 9;
  int ks = T & 7;
  int k = ks * 32 + (l >> 4) * 8 + j;
  int n = l & 15;
  out[idx] = (n < 3) ? f2bf(w2[k * 3 + n]) : (ushort)0;
}

// ================= LDS helpers ================================================
__device__ __forceinline__ short8 ldA16(const ushort* buf, int row, int kbyte) {
  int off = (row * 512 + kbyte) ^ ((row & 7) << 4);
  return *(const short8*)((const char*)buf + off);
}
__device__ __forceinline__ short8 ldA1024(const ushort* buf, int row, int kbyte) {
  int off = (row * 1024 + kbyte) ^ ((row & 7) << 4);
  return *(const short8*)((const char*)buf + off);
}
#define STA(BUF, R, JJ, BITS) { \
    int off_ = ((R) * 512 + (JJ) * 2) ^ (((R) & 7) << 4); \
    (BUF)[off_ >> 1] = (BITS); }
#define STA8(BUF, R, JJ, B8) { \
    int off_ = ((R) * 256 + (JJ)) ^ (((R) & 7) << 3); \
    (BUF)[off_] = (B8); }

// ================= encoder (round-7 verified) =================================
__global__ __launch_bounds__(256) void enc_kernel(
    const float* __restrict__ cv, const float* __restrict__ pv,
    const float* __restrict__ hints,
    const float* __restrict__ w1, const float* __restrict__ b1,
    const ushort* __restrict__ w2p, const float* __restrict__ b2,
    ushort* __restrict__ enc)
{
  __shared__ float fs[32][10];
  __shared__ ushort h1L[32 * 256];
  const long long row0 = (long long)blockIdx.x * 32;
  const int tid = threadIdx.x;
  if (tid < 96) {
    int r = tid / 3, c = tid % 3;
    long long row = row0 + r;
    float a = cv[row * 3 + c];
    fs[r][c]     = a;
    fs[r][3 + c] = a - pv[row * 3 + c];
    fs[r][6 + c] = hints[row * 3 + c];
  }
  __syncthreads();
  {
    const int j = tid;
    float wc[9];
#pragma unroll
    for (int i = 0; i < 9; ++i) wc[i] = w1[i * 256 + j];
    const float bb = b1[j];
    for (int r = 0; r < 32; ++r) {
      float a = bb;
#pragma unroll
      for (int i = 0; i < 9; ++i) a += fs[r][i] * wc[i];
      ushort hb = f2bf(fmaxf(a, 0.f));
      STA(h1L, r, j, hb);
    }
  }
  __syncthreads();
  const int lane = tid & 63, w = tid >> 6;
  const int col = lane & 15, krow = lane >> 4, kb = krow * 16;
  const f32x4 zf4 = {0.f, 0.f, 0.f, 0.f};
  f32x4 acc[2][4];
#pragma unroll
  for (int m = 0; m < 2; ++m)
#pragma unroll
    for (int g = 0; g < 4; ++g) acc[m][g] = zf4;
#pragma unroll
  for (int ks = 0; ks < 8; ++ks) {
    short8 A[2];
#pragma unroll
    for (int m = 0; m < 2; ++m) A[m] = ldA16(h1L, m * 16 + col, ks * 64 + kb);
#pragma unroll
    for (int g = 0; g < 4; ++g) {
      short8 b = *(const short8*)(w2p + ((((w * 4 + g) * 8 + ks) * 64 + lane)) * 8);
#pragma unroll
      for (int m = 0; m < 2; ++m)
        acc[m][g] = __builtin_amdgcn_mfma_f32_16x16x32_bf16(A[m], b, acc[m][g], 0, 0, 0);
    }
  }
#pragma unroll
  for (int g = 0; g < 4; ++g) {
    const int jj = (w * 4 + g) * 16 + col;
    const float bb = b2[jj];
#pragma unroll
    for (int m = 0; m < 2; ++m)
#pragma unroll
      for (int q = 0; q < 4; ++q) {
        long long row = row0 + m * 16 + krow * 4 + q;
        enc[row * 256 + jj] = f2bf(acc[m][g][q] + bb);
      }
  }
}

// ================= seq kernel: fp8 GEMMs ======================================
// A-tile LDS (fp8): [rows][256 B], swizzle byte ^ ((row&7)<<3).
template<int MT>
__device__ __forceinline__ void gemm_main8(
    const u8* __restrict__ W, const u8* __restrict__ AxL,
    const u8* __restrict__ AhL, f32x4 (&acc)[MT][4], int w, int lane)
{
  const int col = lane & 15;
  const int kb  = (lane >> 4) * 8;
  const int sw  = (col & 7) << 3;
#pragma unroll 4
  for (int kp = 0; kp < 8; ++kp) {
    const u8* Ab = (kp < 4) ? AxL : AhL;
    const int ksl = (kp & 3) * 2;
    long a[MT][2];
#pragma unroll
    for (int m = 0; m < MT; ++m) {
      int base = (m * 16 + col) * 256 + ksl * 32 + kb;
      a[m][0] = *(const long*)(Ab + ((base) ^ sw));
      a[m][1] = *(const long*)(Ab + ((base + 32) ^ sw));
    }
#pragma unroll
    for (int g = 0; g < 4; ++g) {
      longx2 bq = *(const longx2*)(W + ((size_t)(((g * 16 + w) * 8 + kp) * 64 + lane) << 4));
#pragma unroll
      for (int m = 0; m < MT; ++m) {
        acc[m][g] = __builtin_amdgcn_mfma_f32_16x16x32_fp8_fp8(a[m][0], bq[0], acc[m][g], 0, 0, 0);
        acc[m][g] = __builtin_amdgcn_mfma_f32_16x16x32_fp8_fp8(a[m][1], bq[1], acc[m][g], 0, 0, 0);
      }
    }
  }
}

__device__ __forceinline__ void gemm_side8(
    const u8* __restrict__ Wbu, const u8* __restrict__ Wfx,
    const u8* __restrict__ Rhb, const u8* __restrict__ AxL,
    f32x4 (&accs)[4], f32x4& accw, int w, int lane)
{
  const int col = lane & 15;
  const int kb  = (lane >> 4) * 8;
  const int sw  = (col & 7) << 3;
#pragma unroll
  for (int kp = 0; kp < 4; ++kp) {
    const int base = col * 256 + kp * 64 + kb;   // ksl*32 = kp*2*32
    long ar0 = *(const long*)(Rhb + ((base) ^ sw));
    long ar1 = *(const long*)(Rhb + ((base + 32) ^ sw));
#pragma unroll
    for (int g = 0; g < 4; ++g) {
      longx2 bq = *(const longx2*)(Wbu + ((size_t)(((g * 16 + w) * 8 + kp + 4) * 64 + lane) << 4));
      accs[g] = __builtin_amdgcn_mfma_f32_16x16x32_fp8_fp8(ar0, bq[0], accs[g], 0, 0, 0);
      accs[g] = __builtin_amdgcn_mfma_f32_16x16x32_fp8_fp8(ar1, bq[1], accs[g], 0, 0, 0);
    }
    long ax0 = *(const long*)(AxL + ((base) ^ sw));
    long ax1 = *(const long*)(AxL + ((base + 32) ^ sw));
    longx2 bw = *(const longx2*)(Wfx + ((size_t)((w * 4 + kp) * 64 + lane) << 4));
    accw = __builtin_amdgcn_mfma_f32_16x16x32_fp8_fp8(ax0, bw[0], accw, 0, 0, 0);
    accw = __builtin_amdgcn_mfma_f32_16x16x32_fp8_fp8(ax1, bw[1], accw, 0, 0, 0);
  }
}

#define ZACC(MT_, A_) { \
  _Pragma("unroll") for (int m_ = 0; m_ < MT_; ++m_) \
  _Pragma("unroll") for (int g_ = 0; g_ < 4; ++g_) A_[m_][g_] = zf4; }

__global__ __launch_bounds__(1024, 4) void seq_kernel(
    const ushort* enc,                      // aliases td_h -> no __restrict__
    const u8* __restrict__ Wbu, const u8* __restrict__ Wtd,
    const u8* __restrict__ Wfx,
    const float* __restrict__ b_iou, const float* __restrict__ b_f,
    const float* __restrict__ b_ih,  const float* __restrict__ b_hh,
    ushort* __restrict__ bu_h, ushort* td_h)
{
  __shared__ u8 Axb[2][32 * 256];
  __shared__ u8 Ahb[2][32 * 256];
  __shared__ u8 Rh[2][16 * 256];

  const int tid  = threadIdx.x;
  const int lane = tid & 63;
  const int w    = tid >> 6;        // wave 0..15
  const int b0   = blockIdx.x * 16;
  const int col  = lane & 15;
  const int krow = lane >> 4;
  const f32x4 zf4 = {0.f, 0.f, 0.f, 0.f};

  const int jj = w * 16 + col;
  const float bi0 = b_iou[jj], bi1 = b_iou[256 + jj], bi2 = b_iou[512 + jj];
  const float bfv = b_f[jj];
  const float bt0 = b_ih[jj]       + b_hh[jj];
  const float bt1 = b_ih[256 + jj] + b_hh[256 + jj];
  const float bt2 = b_ih[512 + jj] + b_hh[512 + jj];
  const float bt3 = b_ih[768 + jj] + b_hh[768 + jj];

  float c2[2][4];
  float rc0[4], rc1[4];
  float sc0[4], sc1[4];

  // staging: one short8 (8 bf16) per thread -> 8 fp8 bytes. T14 split.
#define SLOAD32(V, XV) { \
    int rr_ = tid >> 5, ch_ = tid & 31; \
    int mt_ = rr_ >> 4, br_ = rr_ & 15; \
    long long rowg_ = ((long long)(b0 + br_) * NBv + (mt_ + 1)) * NVv + (V); \
    XV = *(const short8*)(enc + rowg_ * 256 + ch_ * 8); }

#define SLOAD16(V, XV) if (tid < 512) { \
    int rr_ = tid >> 5, ch_ = tid & 31; \
    long long rowg_ = ((long long)(b0 + rr_) * NBv) * NVv + (V); \
    XV = *(const short8*)(enc + rowg_ * 256 + ch_ * 8); }

#define SWRITE(DST, XV, GUARD) if (GUARD) { \
    int rr_ = tid >> 5, ch_ = tid & 31; \
    unsigned long long r_ = 0; \
    _Pragma("unroll") for (int e_ = 0; e_ < 8; ++e_) \
      r_ |= ((unsigned long long)f2fp8(bf2f((ushort)XV[e_]))) << (8 * e_); \
    *(unsigned long long*)((DST) + (((rr_ * 256 + ch_ * 8) ^ ((rr_ & 7) << 3)))) = r_; }

  // ================= PHASE 1: fused bottom-up chains (v 39..0) ===============
  {
    *(unsigned long long*)(&Ahb[0][tid * 8]) = 0ull;
    short8 xv; SLOAD32(CLEN - 1, xv);
#pragma unroll
    for (int m = 0; m < 2; ++m)
#pragma unroll
      for (int q = 0; q < 4; ++q) c2[m][q] = 0.f;
    SWRITE(Axb[0], xv, true);
    __syncthreads();
    for (int s = 0; s < CLEN; ++s) {
      const int v = CLEN - 1 - s, pp = s & 1;
      short8 xn;
      if (s < CLEN - 1) SLOAD32(v - 1, xn);
      f32x4 acc[2][4]; ZACC(2, acc);
      gemm_main8<2>(Wbu, Axb[pp], Ahb[pp], acc, w, lane);
#pragma unroll
      for (int m = 0; m < 2; ++m)
#pragma unroll
        for (int q = 0; q < 4; ++q) {
          const int br = krow * 4 + q;
          float I = acc[m][0][q] + bi0;
          float O = acc[m][1][q] + bi1;
          float U = acc[m][2][q] + bi2;
          float F = acc[m][3][q] + bfv;
          float cn = sigf(I) * tanh_f(U) + sigf(F) * c2[m][q];
          float hn = sigf(O) * tanh_f(cn);
          c2[m][q] = cn;
          u8 hq = f2fp8(hn);
          STA8(Ahb[pp ^ 1], m * 16 + br, jj, hq);
          long long rowg = ((long long)(b0 + br) * NBv + (m + 1)) * NVv + v;
          bu_h[rowg * 256 + jj] = f2bf(hn);
          if (v == 0) {
            STA8(Rh[m], br, jj, hq);
            if (m == 0) rc0[q] = cn; else rc1[q] = cn;
          }
        }
      if (s < CLEN - 1) SWRITE(Axb[pp ^ 1], xn, true);
      __syncthreads();
    }
  }

  // ================= PHASE 2: bottom-up parent chain (v 63..0) ===============
  {
    if (tid < 512) *(unsigned long long*)(&Ahb[0][tid * 8]) = 0ull;
    short8 xv = {};
    SLOAD16(NVv - 1, xv);
#pragma unroll
    for (int q = 0; q < 4; ++q) c2[0][q] = 0.f;
    SWRITE(Axb[0], xv, (tid < 512));
    __syncthreads();
    for (int s = 0; s < NVv; ++s) {
      const int v = NVv - 1 - s, pp = s & 1;
      short8 xn = {};
      if (s < NVv - 1) SLOAD16(v - 1, xn);
      f32x4 acc[1][4]; ZACC(1, acc);
      gemm_main8<1>(Wbu, Axb[pp], Ahb[pp], acc, w, lane);
      const int ck = (v == CI0) ? 0 : ((v == CI1) ? 1 : -1);
      f32x4 accs[4]; f32x4 accw;
      if (ck >= 0) {
#pragma unroll
        for (int g = 0; g < 4; ++g) accs[g] = zf4;
        accw = zf4;
        const u8* Rp = (ck == 0) ? Rh[0] : Rh[1];
        gemm_side8(Wbu, Wfx, Rp, Axb[pp], accs, accw, w, lane);
      }
#pragma unroll
      for (int q = 0; q < 4; ++q) {
        const int br = krow * 4 + q;
        float I  = acc[0][0][q] + bi0;
        float O  = acc[0][1][q] + bi1;
        float U  = acc[0][2][q] + bi2;
        float F1 = acc[0][3][q] + bfv;
        float fc = sigf(F1) * c2[0][q];
        if (ck >= 0) {
          I += accs[0][q]; O += accs[1][q]; U += accs[2][q];
          float wfx = accw[q] + bfv;
          float rcv = (ck == 0) ? rc0[q] : rc1[q];
          fc += sigf(wfx + accs[3][q]) * rcv;
        }
        float cn = sigf(I) * tanh_f(U) + fc;
        float hn = sigf(O) * tanh_f(cn);
        c2[0][q] = cn;
        STA8(Ahb[pp ^ 1], br, jj, f2fp8(hn));
        long long rowg = ((long long)(b0 + br) * NBv) * NVv + v;
        bu_h[rowg * 256 + jj] = f2bf(hn);
        if (v == 0) td_h[rowg * 256 + jj] = f2bf(hn);   // td seed
      }
      if (s < NVv - 1) SWRITE(Axb[pp ^ 1], xn, (tid < 512));
      __syncthreads();
    }
  }
  // phase 2 ended with s=63 (pp=1) -> its epilogue wrote Ahb[0]; c2[0] carries.

  // ================= PHASE 3: top-down parent chain (v 1..63) ================
  {
    short8 xv = {};
    SLOAD16(1, xv);
    SWRITE(Axb[0], xv, (tid < 512));
    __syncthreads();
    for (int s = 0; s < NVv - 1; ++s) {
      const int v = 1 + s, pp = s & 1;
      short8 xn = {};
      if (s < NVv - 2) SLOAD16(v + 1, xn);
      f32x4 acc[1][4]; ZACC(1, acc);
      gemm_main8<1>(Wtd, Axb[pp], Ahb[pp], acc, w, lane);
#pragma unroll
      for (int q = 0; q < 4; ++q) {
        const int br = krow * 4 + q;
        float I = acc[0][0][q] + bt0;
        float F = acc[0][1][q] + bt1;
        float G = acc[0][2][q] + bt2;
        float O = acc[0][3][q] + bt3;
        float cn = sigf(F) * c2[0][q] + sigf(I) * tanh_f(G);
        float hn = sigf(O) * tanh_f(cn);
        c2[0][q] = cn;
        u8 hq = f2fp8(hn);
        STA8(Ahb[pp ^ 1], br, jj, hq);
        long long rowg = ((long long)(b0 + br) * NBv) * NVv + v;
        td_h[rowg * 256 + jj] = f2bf(hn);
        if (v == CI0) { STA8(Rh[0], br, jj, hq); sc0[q] = cn; }
        if (v == CI1) { STA8(Rh[1], br, jj, hq); sc1[q] = cn; }
      }
      if (s < NVv - 2) SWRITE(Axb[pp ^ 1], xn, (tid < 512));
      __syncthreads();
    }
  }

  // ================= PHASE 4: fused top-down chains (v 0..39) ================
  {
    {
      int rr = tid >> 5, ch = tid & 31;
      int mt = rr >> 4, br = rr & 15;
      unsigned long long vv = *(const unsigned long long*)(
          &Rh[mt][0] + (((br * 256 + ch * 8) ^ ((br & 7) << 3))));
      *(unsigned long long*)(&Ahb[0][0] + (((rr * 256 + ch * 8) ^ ((rr & 7) << 3)))) = vv;
    }
    short8 xv; SLOAD32(0, xv);
#pragma unroll
    for (int m = 0; m < 2; ++m)
#pragma unroll
      for (int q = 0; q < 4; ++q)
        c2[m][q] = (m == 0) ? sc0[q] : sc1[q];
    SWRITE(Axb[0], xv, true);
    __syncthreads();
    for (int s = 0; s < CLEN; ++s) {
      const int v = s, pp = s & 1;
      short8 xn;
      if (s < CLEN - 1) SLOAD32(v + 1, xn);
      f32x4 acc[2][4]; ZACC(2, acc);
      gemm_main8<2>(Wtd, Axb[pp], Ahb[pp], acc, w, lane);
#pragma unroll
      for (int m = 0; m < 2; ++m)
#pragma unroll
        for (int q = 0; q < 4; ++q) {
          const int br = krow * 4 + q;
          float I = acc[m][0][q] + bt0;
          float F = acc[m][1][q] + bt1;
          float G = acc[m][2][q] + bt2;
          float O = acc[m][3][q] + bt3;
          float cn = sigf(F) * c2[m][q] + sigf(I) * tanh_f(G);
          float hn = sigf(O) * tanh_f(cn);
          c2[m][q] = cn;
          STA8(Ahb[pp ^ 1], m * 16 + br, jj, f2fp8(hn));
          long long rowg = ((long long)(b0 + br) * NBv + (m + 1)) * NVv + v;
          td_h[rowg * 256 + jj] = f2bf(hn);
        }
      if (s < CLEN - 1) SWRITE(Axb[pp ^ 1], xn, true);
      __syncthreads();
    }
  }
}

// ================= decoder (round-7 verified) =================================
__global__ __launch_bounds__(256) void dec_kernel(
    const ushort* __restrict__ bu_h, const ushort* __restrict__ td_h,
    const float* __restrict__ cv,
    const ushort* __restrict__ w1p, const float* __restrict__ b1,
    const ushort* __restrict__ w2p, const float* __restrict__ b2,
    float* __restrict__ out)
{
  __shared__ ushort combL[32 * 512];
  __shared__ ushort hidL[32 * 256];
  const long long row0 = (long long)blockIdx.x * 32;
  const int tid = threadIdx.x;

#pragma unroll
  for (int h = 0; h < 8; ++h) {
    int cid = tid + h * 256;
    int rr = cid >> 6, ch = cid & 63;
    long long row = row0 + rr;
    short8 v = (ch < 32)
        ? *(const short8*)(bu_h + row * 256 + ch * 8)
        : *(const short8*)(td_h + row * 256 + (ch - 32) * 8);
    *(short8*)((char*)combL + ((rr * 1024 + ch * 16) ^ ((rr & 7) << 4))) = v;
  }
  __syncthreads();

  const int lane = tid & 63, w = tid >> 6;
  const int col = lane & 15, krow = lane >> 4, kb = krow * 16;
  const f32x4 zf4 = {0.f, 0.f, 0.f, 0.f};
  f32x4 acc[2][4];
#pragma unroll
  for (int m = 0; m < 2; ++m)
#pragma unroll
    for (int g = 0; g < 4; ++g) acc[m][g] = zf4;
#pragma unroll 4
  for (int ks = 0; ks < 16; ++ks) {
    short8 A[2];
#pragma unroll
    for (int m = 0; m < 2; ++m) A[m] = ldA1024(combL, m * 16 + col, ks * 64 + kb);
#pragma unroll
    for (int g = 0; g < 4; ++g) {
      short8 b = *(const short8*)(w1p + ((((w * 4 + g) * 16 + ks) * 64 + lane)) * 8);
#pragma unroll
      for (int m = 0; m < 2; ++m)
        acc[m][g] = __builtin_amdgcn_mfma_f32_16x16x32_bf16(A[m], b, acc[m][g], 0, 0, 0);
    }
  }
#pragma unroll
  for (int g = 0; g < 4; ++g) {
    const int jj = (w * 4 + g) * 16 + col;
    const float bb = b1[jj];
#pragma unroll
    for (int m = 0; m < 2; ++m)
#pragma unroll
      for (int q = 0; q < 4; ++q) {
        ushort hb = f2bf(fmaxf(acc[m][g][q] + bb, 0.f));
        STA(hidL, m * 16 + krow * 4 + q, jj, hb);
      }
  }
  __syncthreads();

  if (w == 0) {
    f32x4 acc2[2]; acc2[0] = zf4; acc2[1] = zf4;
#pragma unroll
    for (int ks = 0; ks < 8; ++ks) {
      short8 bv = *(const short8*)(w2p + ((ks * 64 + lane)) * 8);
#pragma unroll
      for (int m = 0; m < 2; ++m) {
        short8 A = ldA16(hidL, m * 16 + col, ks * 64 + kb);
        acc2[m] = __builtin_amdgcn_mfma_f32_16x16x32_bf16(A, bv, acc2[m], 0, 0, 0);
      }
    }
    if (col < 3) {
      const float bb = b2[col];
#pragma unroll
      for (int m = 0; m < 2; ++m)
#pragma unroll
        for (int q = 0; q < 4; ++q) {
          long long row = row0 + m * 16 + krow * 4 + q;
          int v  = (int)(row & 63);
          int br = (int)((row >> 6) % 3);
          float res = 0.f;
          if (br == 0 || v < CLEN)
            res = cv[row * 3 + col] + acc2[m][q] + bb;
          out[row * 3 + col] = res;
        }
    }
  }
}

extern "C" void kernel_launch(void* const* d_in, const int* in_sizes, int n_in,
                              void* d_out, int out_size, void* d_ws, size_t ws_size,
                              hipStream_t stream) {
  const float* cv     = (const float*)d_in[0];
  const float* pv     = (const float*)d_in[1];
  const float* hints  = (const float*)d_in[2];
  const float* enc_w1 = (const float*)d_in[3];
  const float* enc_b1 = (const float*)d_in[4];
  const float* enc_w2 = (const float*)d_in[5];
  const float* enc_b2 = (const float*)d_in[6];
  const float* W_iou  = (const float*)d_in[7];
  const float* b_iou  = (const float*)d_in[8];
  const float* U_iou  = (const float*)d_in[9];
  const float* W_f    = (const float*)d_in[10];
  const float* b_f    = (const float*)d_in[11];
  const float* U_f    = (const float*)d_in[12];
  const float* W_ih   = (const float*)d_in[13];
  const float* b_ih   = (const float*)d_in[14];
  const float* W_hh   = (const float*)d_in[15];
  const float* b_hh   = (const float*)d_in[16];
  const float* dec_w1 = (const float*)d_in[17];
  const float* dec_b1 = (const float*)d_in[18];
  const float* dec_w2 = (const float*)d_in[19];
  const float* dec_b2 = (const float*)d_in[20];

  size_t act = (size_t)NROWS * 256;
  size_t need = 2 * act * 2                       // encW + buh (bf16)
              + 2 * (size_t)524288 + 65536        // Wbu8 + Wtd8 + Wfx8 (fp8)
              + (65536 + 131072 + 4096) * 2;      // enc/dec bf16 packs
  if (ws_size < need) return;

  ushort* encW   = (ushort*)d_ws;     // enc, overwritten in place as td_h
  ushort* buh    = encW + act;
  u8*     Wbu8   = (u8*)(buh + act);
  u8*     Wtd8   = Wbu8 + 524288;
  u8*     Wfx8   = Wtd8 + 524288;
  ushort* encw2p = (ushort*)(Wfx8 + 65536);
  ushort* decw1p = encw2p + 65536;
  ushort* decw2p = decw1p + 131072;

  pack_bu8_kernel<<<256, 256, 0, stream>>>(W_iou, W_f, U_iou, U_f, Wbu8);
  pack_td8_kernel<<<256, 256, 0, stream>>>(W_ih, W_hh, Wtd8);
  pack_wfx8_kernel<<<32, 256, 0, stream>>>(W_f, Wfx8);
  pack_encw2_kernel<<<256, 256, 0, stream>>>(enc_w2, encw2p);
  pack_decw1_kernel<<<512, 256, 0, stream>>>(dec_w1, decw1p);
  pack_decw2_kernel<<<16, 256, 0, stream>>>(dec_w2, decw2p);

  enc_kernel<<<(int)(NROWS / 32), 256, 0, stream>>>(cv, pv, hints, enc_w1, enc_b1,
                                                    encw2p, enc_b2, encW);
  seq_kernel<<<BATCH / 16, 1024, 0, stream>>>(encW, Wbu8, Wtd8, Wfx8, b_iou, b_f,
                                              b_ih, b_hh, buh, encW);
  dec_kernel<<<(int)(NROWS / 32), 256, 0, stream>>>(buh, encW, cv, decw1p, dec_b1,
                                                    decw2p, dec_b2, (float*)d_out);
}